// Round 6
// baseline (2468.727 us; speedup 1.0000x reference)
//
#include <hip/hip_runtime.h>
#include <math.h>

#define B_ 16
#define H_ 512
#define L_ 2048
#define N_ 64
#define CD_ 128

typedef unsigned int u32;
typedef unsigned short u16;

__device__ __forceinline__ float gelu_f(float v) {
    return 0.5f * v * (1.0f + erff(v * 0.70710678118654752f));
}

// ---------------------------------------------------------------- sentinel fill
__global__ void k_fill(float* __restrict__ out, int n, float val) {
    int i = blockIdx.x * 256 + threadIdx.x;
    if (i < n) out[i] = val;
}

// ---------------------------------------------------------------- K (f32 closed form)
// K[h][l] = 2 * Re( sum_n Cm[h,n] * exp(dtA[h,n] * l) )
__global__ void k_compute_K(const float* __restrict__ log_dt,
                            const float* __restrict__ C_ri,
                            const float* __restrict__ log_A_real,
                            const float* __restrict__ A_imag,
                            float* __restrict__ Kbuf) {
    int h = blockIdx.x;
    __shared__ float dre[N_], dim[N_], cre[N_], cim[N_];
    int t = threadIdx.x;
    if (t < N_) {
        float dt = expf(log_dt[h]);
        float a_re = -expf(log_A_real[h * N_ + t]);
        float a_im = A_imag[h * N_ + t];
        float dA_re = a_re * dt, dA_im = a_im * dt;
        float er = expf(dA_re);
        float s, c;
        sincosf(dA_im, &s, &c);
        float num_re = er * c - 1.0f, num_im = er * s;
        float den = a_re * a_re + a_im * a_im;
        float q_re = (num_re * a_re + num_im * a_im) / den;
        float q_im = (num_im * a_re - num_re * a_im) / den;
        float Cr = C_ri[(h * N_ + t) * 2 + 0];
        float Ci = C_ri[(h * N_ + t) * 2 + 1];
        cre[t] = Cr * q_re - Ci * q_im;
        cim[t] = Cr * q_im + Ci * q_re;
        dre[t] = dA_re; dim[t] = dA_im;
    }
    __syncthreads();
    for (int l = t; l < L_; l += blockDim.x) {
        float fl = (float)l;
        float acc = 0.f;
        for (int n = 0; n < N_; ++n) {
            float er = expf(dre[n] * fl);
            float s, c;
            sincosf(dim[n] * fl, &s, &c);
            acc += er * (cre[n] * c - cim[n] * s);
        }
        Kbuf[(size_t)h * L_ + l] = 2.0f * acc;
    }
}

// ---------------------------------------------------------------- FiLM
__global__ void k_film(const float* __restrict__ cond,
                       const float* __restrict__ film_w,
                       const float* __restrict__ film_b,
                       float* __restrict__ gb) {
    int j = blockIdx.x * 256 + threadIdx.x;   // 0 .. B*2H-1
    int b  = j >> 10;
    int jj = j & 1023;
    float acc = film_b[jj];
    for (int c = 0; c < CD_; ++c)
        acc += cond[b * CD_ + c] * film_w[jj * CD_ + c];
    gb[j] = acc;
}

// ---------------------------------------------------------------- matmul + gelu (f32 out)
__global__ __launch_bounds__(256) void k_linear(
    const float* __restrict__ x, const float* __restrict__ W,
    const float* __restrict__ bias, float* __restrict__ hbuf) {
    int b  = blockIdx.z;
    int g0 = blockIdx.y * 16;
    int l  = blockIdx.x * 256 + threadIdx.x;
    __shared__ float Ws[16][H_];
    for (int i = threadIdx.x; i < 16 * H_; i += 256)
        Ws[i >> 9][i & (H_ - 1)] = W[(size_t)(g0 + (i >> 9)) * H_ + (i & (H_ - 1))];
    __syncthreads();
    float acc[16];
    #pragma unroll
    for (int gg = 0; gg < 16; ++gg) acc[gg] = 0.f;
    for (int k = 0; k < H_; ++k) {
        float xv = x[((size_t)b * H_ + k) * L_ + l];
        #pragma unroll
        for (int gg = 0; gg < 16; ++gg) acc[gg] += Ws[gg][k] * xv;
    }
    for (int gg = 0; gg < 16; ++gg)
        hbuf[((size_t)b * H_ + g0 + gg) * L_ + l] = gelu_f(acc[gg] + bias[g0 + gg]);
}

// ---------------------------------------------------------------- conv + D*h (in-place f32)
__global__ __launch_bounds__(256) void k_conv(
    float* __restrict__ hy, const float* __restrict__ Kbuf,
    const float* __restrict__ Dp) {
    int bg = blockIdx.x;            // b*H + g
    int g = bg & (H_ - 1);
    __shared__ float hp[2 * L_];    // hp[2047 + i] = h[i]; hp[0..2046] = 0
    __shared__ float Ks[L_];
    int t = threadIdx.x;

    const float* hrow = hy + (size_t)bg * L_;
    for (int i = t; i < L_ - 1; i += 256) hp[i] = 0.0f;
    for (int i = t; i < L_; i += 256) {
        hp[(L_ - 1) + i] = hrow[i];
        Ks[i] = Kbuf[(size_t)g * L_ + i];
    }
    __syncthreads();

    float acc[8] = {0.f, 0.f, 0.f, 0.f, 0.f, 0.f, 0.f, 0.f};
    for (int m = 0; m < L_; ++m) {
        float kv = Ks[m];                       // wave-uniform broadcast
        #pragma unroll
        for (int jj = 0; jj < 8; ++jj)
            acc[jj] += kv * hp[(L_ - 1) + t + 256 * jj - m];  // stride-1 across lanes
    }

    float Dg = Dp[g];
    for (int jj = 0; jj < 8; ++jj) {
        int l = t + 256 * jj;
        hy[(size_t)bg * L_ + l] = acc[jj] + Dg * hp[(L_ - 1) + l];
    }
}

// ---------------------------------------------------------------- stats, fp64 per channel
__global__ __launch_bounds__(256) void k_stats2(const float* __restrict__ hy,
                                                float* __restrict__ stats) {
    int g = blockIdx.x;                 // one block per channel
    int t = threadIdx.x;
    double s = 0.0, ss = 0.0;
    for (int i = t; i < B_ * L_; i += 256) {
        int b = i >> 11, l = i & (L_ - 1);
        double y = (double)hy[((size_t)(b * H_ + g)) * L_ + l];
        s += y; ss += y * y;
    }
    __shared__ double sh_s[256], sh_q[256];
    sh_s[t] = s; sh_q[t] = ss;
    __syncthreads();
    for (int off = 128; off > 0; off >>= 1) {
        if (t < off) { sh_s[t] += sh_s[t + off]; sh_q[t] += sh_q[t + off]; }
        __syncthreads();
    }
    if (t == 0) {
        double inv = 1.0 / (double)(B_ * L_);
        double mean = sh_s[0] * inv;
        double var = sh_q[0] * inv - mean * mean;
        stats[g * 2 + 0] = (float)mean;
        stats[g * 2 + 1] = (float)rsqrt(var + 1e-5);
    }
}

// ---------------------------------------------------------------- BN + FiLM + gelu + residual (in-place f32)
__global__ __launch_bounds__(256) void k_final2(
    float* __restrict__ out, const float* __restrict__ x,
    const float* __restrict__ stats, const float* __restrict__ gb,
    const float* __restrict__ res_w) {
    size_t idx = (size_t)blockIdx.x * 256 + threadIdx.x;
    int bg = (int)(idx >> 11);          // / L
    int g = bg & (H_ - 1);
    int b = bg >> 9;
    float y = out[idx];
    float yn = (y - stats[g * 2 + 0]) * stats[g * 2 + 1];
    float z = yn * gb[b * (2 * H_) + g] + gb[b * (2 * H_) + H_ + g];
    out[idx] = gelu_f(z) + x[idx] * res_w[g];
}

// ---------------------------------------------------------------- launch
extern "C" void kernel_launch(void* const* d_in, const int* in_sizes, int n_in,
                              void* d_out, int out_size, void* d_ws, size_t ws_size,
                              hipStream_t stream) {
    // tripwire 1: input element counts must match setup_inputs() order
    const int expect[12] = {16777216, 2048, 262144, 512, 512, 65536,
                            32768, 32768, 512, 131072, 1024, 512};
    bool ok = (n_in == 12);
    if (ok) for (int i = 0; i < 12; ++i) if (in_sizes[i] != expect[i]) ok = false;
    if (!ok) {
        k_fill<<<(out_size + 255) / 256, 256, 0, stream>>>((float*)d_out, out_size, 1000.0f);
        return;
    }
    // tripwire 2: workspace size (~4.2 MB needed)
    if (ws_size < ((size_t)H_ * L_ * 4 + (size_t)H_ * 2 * 4 + (size_t)B_ * 2 * H_ * 4 + 1024)) {
        k_fill<<<(out_size + 255) / 256, 256, 0, stream>>>((float*)d_out, out_size, 2000.0f);
        return;
    }

    // Inputs are float32 (reference dtypes), dict order.
    const float* x          = (const float*)d_in[0];
    const float* cond       = (const float*)d_in[1];
    const float* linear_w   = (const float*)d_in[2];
    const float* linear_b   = (const float*)d_in[3];
    const float* log_dt     = (const float*)d_in[4];
    const float* C_ri       = (const float*)d_in[5];
    const float* log_A_real = (const float*)d_in[6];
    const float* A_imag     = (const float*)d_in[7];
    const float* Dp         = (const float*)d_in[8];
    const float* film_w     = (const float*)d_in[9];
    const float* film_b     = (const float*)d_in[10];
    const float* res_w      = (const float*)d_in[11];

    // Output is float32 (reference output dtype). d_out doubles as h/y buffer.
    float* hy = (float*)d_out;

    char* w = (char*)d_ws;
    float* Kbuf  = (float*)w;  w += (size_t)H_ * L_ * 4;        // 4 MB
    float* stats = (float*)w;  w += (size_t)H_ * 2 * 4;         // 4 KB
    float* gb    = (float*)w;  w += (size_t)B_ * 2 * H_ * 4;    // 64 KB

    k_compute_K<<<H_, 256, 0, stream>>>(log_dt, C_ri, log_A_real, A_imag, Kbuf);
    k_film<<<(B_ * 2 * H_) / 256, 256, 0, stream>>>(cond, film_w, film_b, gb);
    dim3 gmm(L_ / 256, H_ / 16, B_);
    k_linear<<<gmm, 256, 0, stream>>>(x, linear_w, linear_b, hy);
    k_conv<<<B_ * H_, 256, 0, stream>>>(hy, Kbuf, Dp);
    k_stats2<<<H_, 256, 0, stream>>>(hy, stats);
    k_final2<<<(int)(((size_t)B_ * H_ * L_) / 256), 256, 0, stream>>>(
        hy, x, stats, gb, res_w);
}

// Round 7
// 1283.995 us; speedup vs baseline: 1.9227x; 1.9227x over previous
//
#include <hip/hip_runtime.h>
#include <math.h>

#define B_ 16
#define H_ 512
#define L_ 2048
#define N_ 64
#define CD_ 128

typedef unsigned int u32;
typedef unsigned short u16;

__device__ __forceinline__ float gelu_f(float v) {
    return 0.5f * v * (1.0f + erff(v * 0.70710678118654752f));
}

// ---------------------------------------------------------------- sentinel fill
__global__ void k_fill(float* __restrict__ out, int n, float val) {
    int i = blockIdx.x * 256 + threadIdx.x;
    if (i < n) out[i] = val;
}

// ---------------------------------------------------------------- K (f32 closed form)
__global__ void k_compute_K(const float* __restrict__ log_dt,
                            const float* __restrict__ C_ri,
                            const float* __restrict__ log_A_real,
                            const float* __restrict__ A_imag,
                            float* __restrict__ Kbuf) {
    int h = blockIdx.x;
    __shared__ float dre[N_], dim[N_], cre[N_], cim[N_];
    int t = threadIdx.x;
    if (t < N_) {
        float dt = expf(log_dt[h]);
        float a_re = -expf(log_A_real[h * N_ + t]);
        float a_im = A_imag[h * N_ + t];
        float dA_re = a_re * dt, dA_im = a_im * dt;
        float er = expf(dA_re);
        float s, c;
        sincosf(dA_im, &s, &c);
        float num_re = er * c - 1.0f, num_im = er * s;
        float den = a_re * a_re + a_im * a_im;
        float q_re = (num_re * a_re + num_im * a_im) / den;
        float q_im = (num_im * a_re - num_re * a_im) / den;
        float Cr = C_ri[(h * N_ + t) * 2 + 0];
        float Ci = C_ri[(h * N_ + t) * 2 + 1];
        cre[t] = Cr * q_re - Ci * q_im;
        cim[t] = Cr * q_im + Ci * q_re;
        dre[t] = dA_re; dim[t] = dA_im;
    }
    __syncthreads();
    for (int l = t; l < L_; l += blockDim.x) {
        float fl = (float)l;
        float acc = 0.f;
        for (int n = 0; n < N_; ++n) {
            float er = expf(dre[n] * fl);
            float s, c;
            sincosf(dim[n] * fl, &s, &c);
            acc += er * (cre[n] * c - cim[n] * s);
        }
        Kbuf[(size_t)h * L_ + l] = 2.0f * acc;
    }
}

// ---------------------------------------------------------------- FiLM
__global__ void k_film(const float* __restrict__ cond,
                       const float* __restrict__ film_w,
                       const float* __restrict__ film_b,
                       float* __restrict__ gb) {
    int j = blockIdx.x * 256 + threadIdx.x;   // 0 .. B*2H-1
    int b  = j >> 10;
    int jj = j & 1023;
    float acc = film_b[jj];
    for (int c = 0; c < CD_; ++c)
        acc += cond[b * CD_ + c] * film_w[jj * CD_ + c];
    gb[j] = acc;
}

// ---------------------------------------------------------------- matmul + gelu (128x128 tile, 8x8 reg block)
#define BM 128
#define BLT 128
#define BK 16
__global__ __launch_bounds__(256) void k_linear(
    const float* __restrict__ x, const float* __restrict__ W,
    const float* __restrict__ bias, float* __restrict__ hbuf) {
    int b  = blockIdx.z;
    int g0 = blockIdx.y * BM;
    int l0 = blockIdx.x * BLT;
    __shared__ float As[BK][BM + 4];   // As[k][g]
    __shared__ float Bs[BK][BLT + 4];  // Bs[k][l]
    int tid = threadIdx.x;
    int tx = tid & 15, ty = tid >> 4;
    float acc[8][8] = {};
    for (int k0 = 0; k0 < H_; k0 += BK) {
        #pragma unroll
        for (int i = 0; i < 2; ++i) {
            int e = tid + 256 * i;          // 0..511 float4s
            int g = e >> 2, kq = (e & 3) * 4;
            float4 w4 = *(const float4*)&W[(size_t)(g0 + g) * H_ + k0 + kq];
            As[kq + 0][g] = w4.x; As[kq + 1][g] = w4.y;
            As[kq + 2][g] = w4.z; As[kq + 3][g] = w4.w;
        }
        #pragma unroll
        for (int i = 0; i < 2; ++i) {
            int e = tid + 256 * i;
            int k = e >> 5, c = (e & 31) * 4;
            *(float4*)&Bs[k][c] =
                *(const float4*)&x[((size_t)b * H_ + k0 + k) * L_ + l0 + c];
        }
        __syncthreads();
        #pragma unroll
        for (int k = 0; k < BK; ++k) {
            float4 a0 = *(const float4*)&As[k][ty * 8];
            float4 a1 = *(const float4*)&As[k][ty * 8 + 4];
            float4 b0 = *(const float4*)&Bs[k][tx * 8];
            float4 b1 = *(const float4*)&Bs[k][tx * 8 + 4];
            float av[8] = {a0.x, a0.y, a0.z, a0.w, a1.x, a1.y, a1.z, a1.w};
            float bv[8] = {b0.x, b0.y, b0.z, b0.w, b1.x, b1.y, b1.z, b1.w};
            #pragma unroll
            for (int i = 0; i < 8; ++i)
                #pragma unroll
                for (int j = 0; j < 8; ++j) acc[i][j] += av[i] * bv[j];
        }
        __syncthreads();
    }
    #pragma unroll
    for (int i = 0; i < 8; ++i) {
        int g = g0 + ty * 8 + i;
        float bi = bias[g];
        float4 o0, o1;
        o0.x = gelu_f(acc[i][0] + bi); o0.y = gelu_f(acc[i][1] + bi);
        o0.z = gelu_f(acc[i][2] + bi); o0.w = gelu_f(acc[i][3] + bi);
        o1.x = gelu_f(acc[i][4] + bi); o1.y = gelu_f(acc[i][5] + bi);
        o1.z = gelu_f(acc[i][6] + bi); o1.w = gelu_f(acc[i][7] + bi);
        float* dst = &hbuf[((size_t)b * H_ + g) * L_ + l0 + tx * 8];
        *(float4*)dst = o0;
        *(float4*)(dst + 4) = o1;
    }
}

// ---------------------------------------------------------------- conv + D*h, register-blocked
// Thread owns 16 contiguous l's; 8-wide m chunks; swizzled LDS pos(v)=v+(v>>4).
__global__ __launch_bounds__(128) void k_conv16(
    float* __restrict__ hy, const float* __restrict__ Kbuf,
    const float* __restrict__ Dp) {
    int bg = blockIdx.x;            // b*H + g
    int g = bg & (H_ - 1);
    __shared__ float hs[2192];      // pos(v) = v + (v>>4), v = i + 16, i in [-16, 2047]
    __shared__ float Ks[L_];
    int t = threadIdx.x;

    const float* hrow = hy + (size_t)bg * L_;
    #pragma unroll
    for (int c = 0; c < 16; ++c) {
        int v = t * 16 + c + 16;
        hs[v + (v >> 4)] = hrow[t * 16 + c];
    }
    if (t < 16) hs[t] = 0.0f;       // pos(v)=v for v<16 : logical i in [-16,-1]
    for (int i = t; i < L_; i += 128) Ks[i] = Kbuf[(size_t)g * L_ + i];
    __syncthreads();

    const int lb = t * 16;
    float acc[16] = {};
    const int m0max = lb + 8;       // covers m up to lb+15 = largest l of this thread
    for (int m0 = 0; m0 <= m0max; m0 += 8) {
        float kv[8], hv[23];
        #pragma unroll
        for (int s = 0; s < 8; ++s) kv[s] = Ks[m0 + s];     // wave-uniform broadcast
        #pragma unroll
        for (int r = 0; r < 23; ++r) {
            int v = lb - m0 + 9 + r;                        // logical i = lb-m0-7+r
            hv[r] = hs[v + (v >> 4)];
        }
        #pragma unroll
        for (int s = 0; s < 8; ++s)
            #pragma unroll
            for (int j = 0; j < 16; ++j)
                acc[j] += kv[s] * hv[j - s + 7];            // i = lb+j-m0-s
    }

    float Dg = Dp[g];
    #pragma unroll
    for (int j = 0; j < 16; ++j) {
        int v = lb + j + 16;
        acc[j] += Dg * hs[v + (v >> 4)];
    }
    float* dst = hy + (size_t)bg * L_ + lb;
    #pragma unroll
    for (int j = 0; j < 16; ++j) dst[j] = acc[j];
}

// ---------------------------------------------------------------- stats, fp64 per channel
__global__ __launch_bounds__(256) void k_stats2(const float* __restrict__ hy,
                                                float* __restrict__ stats) {
    int g = blockIdx.x;
    int t = threadIdx.x;
    double s = 0.0, ss = 0.0;
    for (int i = t; i < B_ * L_; i += 256) {
        int b = i >> 11, l = i & (L_ - 1);
        double y = (double)hy[((size_t)(b * H_ + g)) * L_ + l];
        s += y; ss += y * y;
    }
    __shared__ double sh_s[256], sh_q[256];
    sh_s[t] = s; sh_q[t] = ss;
    __syncthreads();
    for (int off = 128; off > 0; off >>= 1) {
        if (t < off) { sh_s[t] += sh_s[t + off]; sh_q[t] += sh_q[t + off]; }
        __syncthreads();
    }
    if (t == 0) {
        double inv = 1.0 / (double)(B_ * L_);
        double mean = sh_s[0] * inv;
        double var = sh_q[0] * inv - mean * mean;
        stats[g * 2 + 0] = (float)mean;
        stats[g * 2 + 1] = (float)rsqrt(var + 1e-5);
    }
}

// ---------------------------------------------------------------- BN + FiLM + gelu + residual
__global__ __launch_bounds__(256) void k_final2(
    float* __restrict__ out, const float* __restrict__ x,
    const float* __restrict__ stats, const float* __restrict__ gb,
    const float* __restrict__ res_w) {
    size_t idx = (size_t)blockIdx.x * 256 + threadIdx.x;
    int bg = (int)(idx >> 11);
    int g = bg & (H_ - 1);
    int b = bg >> 9;
    float y = out[idx];
    float yn = (y - stats[g * 2 + 0]) * stats[g * 2 + 1];
    float z = yn * gb[b * (2 * H_) + g] + gb[b * (2 * H_) + H_ + g];
    out[idx] = gelu_f(z) + x[idx] * res_w[g];
}

// ---------------------------------------------------------------- launch
extern "C" void kernel_launch(void* const* d_in, const int* in_sizes, int n_in,
                              void* d_out, int out_size, void* d_ws, size_t ws_size,
                              hipStream_t stream) {
    const int expect[12] = {16777216, 2048, 262144, 512, 512, 65536,
                            32768, 32768, 512, 131072, 1024, 512};
    bool ok = (n_in == 12);
    if (ok) for (int i = 0; i < 12; ++i) if (in_sizes[i] != expect[i]) ok = false;
    if (!ok) {
        k_fill<<<(out_size + 255) / 256, 256, 0, stream>>>((float*)d_out, out_size, 1000.0f);
        return;
    }
    if (ws_size < ((size_t)H_ * L_ * 4 + (size_t)H_ * 2 * 4 + (size_t)B_ * 2 * H_ * 4 + 1024)) {
        k_fill<<<(out_size + 255) / 256, 256, 0, stream>>>((float*)d_out, out_size, 2000.0f);
        return;
    }

    const float* x          = (const float*)d_in[0];
    const float* cond       = (const float*)d_in[1];
    const float* linear_w   = (const float*)d_in[2];
    const float* linear_b   = (const float*)d_in[3];
    const float* log_dt     = (const float*)d_in[4];
    const float* C_ri       = (const float*)d_in[5];
    const float* log_A_real = (const float*)d_in[6];
    const float* A_imag     = (const float*)d_in[7];
    const float* Dp         = (const float*)d_in[8];
    const float* film_w     = (const float*)d_in[9];
    const float* film_b     = (const float*)d_in[10];
    const float* res_w      = (const float*)d_in[11];

    float* hy = (float*)d_out;   // h -> y -> final, f32, B*H*L

    char* w = (char*)d_ws;
    float* Kbuf  = (float*)w;  w += (size_t)H_ * L_ * 4;        // 4 MB
    float* stats = (float*)w;  w += (size_t)H_ * 2 * 4;         // 4 KB
    float* gb    = (float*)w;  w += (size_t)B_ * 2 * H_ * 4;    // 64 KB

    k_compute_K<<<H_, 256, 0, stream>>>(log_dt, C_ri, log_A_real, A_imag, Kbuf);
    k_film<<<(B_ * 2 * H_) / 256, 256, 0, stream>>>(cond, film_w, film_b, gb);
    dim3 gmm(L_ / BLT, H_ / BM, B_);
    k_linear<<<gmm, 256, 0, stream>>>(x, linear_w, linear_b, hy);
    k_conv16<<<B_ * H_, 128, 0, stream>>>(hy, Kbuf, Dp);
    k_stats2<<<H_, 256, 0, stream>>>(hy, stats);
    k_final2<<<(int)(((size_t)B_ * H_ * L_) / 256), 256, 0, stream>>>(
        hy, x, stats, gb, res_w);
}

// Round 8
// 424.460 us; speedup vs baseline: 5.8162x; 3.0250x over previous
//
#include <hip/hip_runtime.h>
#include <math.h>

#define B_ 16
#define H_ 512
#define L_ 2048
#define N_ 64
#define CD_ 128
#define PITCH 2052   // bf16 elements per H_lds row (+4 pad -> stride 2 banks, conflict-free)

typedef unsigned int u32;
typedef unsigned short u16;
typedef __attribute__((ext_vector_type(8))) short bf16x8;   // 8 bf16 in 4 VGPRs
typedef __attribute__((ext_vector_type(4))) float f32x4;    // mfma 16x16x32 C/D

__device__ __forceinline__ float gelu_f(float v) {
    return 0.5f * v * (1.0f + erff(v * 0.70710678118654752f));
}
__device__ __forceinline__ float bf2f(u16 b) {
    union { u32 u; float f; } c; c.u = ((u32)b) << 16; return c.f;
}
__device__ __forceinline__ u16 f2bf(float f) {
    union { float f; u32 u; } c; c.f = f;
    u32 u = c.u;
    return (u16)((u + 0x7FFFu + ((u >> 16) & 1u)) >> 16);
}
__device__ __forceinline__ u32 pack2(float a, float b) {
    return (u32)f2bf(a) | ((u32)f2bf(b) << 16);
}

// ---------------------------------------------------------------- sentinel fill
__global__ void k_fill(float* __restrict__ out, int n, float val) {
    int i = blockIdx.x * 256 + threadIdx.x;
    if (i < n) out[i] = val;
}

// ---------------------------------------------------------------- K (f32 closed form)
__global__ void k_compute_K(const float* __restrict__ log_dt,
                            const float* __restrict__ C_ri,
                            const float* __restrict__ log_A_real,
                            const float* __restrict__ A_imag,
                            float* __restrict__ Kbuf) {
    int h = blockIdx.x;
    __shared__ float dre[N_], dim[N_], cre[N_], cim[N_];
    int t = threadIdx.x;
    if (t < N_) {
        float dt = expf(log_dt[h]);
        float a_re = -expf(log_A_real[h * N_ + t]);
        float a_im = A_imag[h * N_ + t];
        float dA_re = a_re * dt, dA_im = a_im * dt;
        float er = expf(dA_re);
        float s, c;
        sincosf(dA_im, &s, &c);
        float num_re = er * c - 1.0f, num_im = er * s;
        float den = a_re * a_re + a_im * a_im;
        float q_re = (num_re * a_re + num_im * a_im) / den;
        float q_im = (num_im * a_re - num_re * a_im) / den;
        float Cr = C_ri[(h * N_ + t) * 2 + 0];
        float Ci = C_ri[(h * N_ + t) * 2 + 1];
        cre[t] = Cr * q_re - Ci * q_im;
        cim[t] = Cr * q_im + Ci * q_re;
        dre[t] = dA_re; dim[t] = dA_im;
    }
    __syncthreads();
    for (int l = t; l < L_; l += blockDim.x) {
        float fl = (float)l;
        float acc = 0.f;
        for (int n = 0; n < N_; ++n) {
            float er = expf(dre[n] * fl);
            float s, c;
            sincosf(dim[n] * fl, &s, &c);
            acc += er * (cre[n] * c - cim[n] * s);
        }
        Kbuf[(size_t)h * L_ + l] = 2.0f * acc;
    }
}

// ---------------------------------------------------------------- FiLM
__global__ void k_film(const float* __restrict__ cond,
                       const float* __restrict__ film_w,
                       const float* __restrict__ film_b,
                       float* __restrict__ gb) {
    int j = blockIdx.x * 256 + threadIdx.x;   // 0 .. B*2H-1
    int b  = j >> 10;
    int jj = j & 1023;
    float acc = film_b[jj];
    for (int c = 0; c < CD_; ++c)
        acc += cond[b * CD_ + c] * film_w[jj * CD_ + c];
    gb[j] = acc;
}

// ---------------------------------------------------------------- matmul + gelu (128x128 tile, 8x8 reg block)
#define BM 128
#define BLT 128
#define BK 16
__global__ __launch_bounds__(256) void k_linear(
    const float* __restrict__ x, const float* __restrict__ W,
    const float* __restrict__ bias, float* __restrict__ hbuf) {
    int b  = blockIdx.z;
    int g0 = blockIdx.y * BM;
    int l0 = blockIdx.x * BLT;
    __shared__ float As[BK][BM + 4];   // As[k][g]
    __shared__ float Bs[BK][BLT + 4];  // Bs[k][l]
    int tid = threadIdx.x;
    int tx = tid & 15, ty = tid >> 4;
    float acc[8][8] = {};
    for (int k0 = 0; k0 < H_; k0 += BK) {
        #pragma unroll
        for (int i = 0; i < 2; ++i) {
            int e = tid + 256 * i;          // 0..511 float4s
            int g = e >> 2, kq = (e & 3) * 4;
            float4 w4 = *(const float4*)&W[(size_t)(g0 + g) * H_ + k0 + kq];
            As[kq + 0][g] = w4.x; As[kq + 1][g] = w4.y;
            As[kq + 2][g] = w4.z; As[kq + 3][g] = w4.w;
        }
        #pragma unroll
        for (int i = 0; i < 2; ++i) {
            int e = tid + 256 * i;
            int k = e >> 5, c = (e & 31) * 4;
            *(float4*)&Bs[k][c] =
                *(const float4*)&x[((size_t)b * H_ + k0 + k) * L_ + l0 + c];
        }
        __syncthreads();
        #pragma unroll
        for (int k = 0; k < BK; ++k) {
            float4 a0 = *(const float4*)&As[k][ty * 8];
            float4 a1 = *(const float4*)&As[k][ty * 8 + 4];
            float4 b0 = *(const float4*)&Bs[k][tx * 8];
            float4 b1 = *(const float4*)&Bs[k][tx * 8 + 4];
            float av[8] = {a0.x, a0.y, a0.z, a0.w, a1.x, a1.y, a1.z, a1.w};
            float bv[8] = {b0.x, b0.y, b0.z, b0.w, b1.x, b1.y, b1.z, b1.w};
            #pragma unroll
            for (int i = 0; i < 8; ++i)
                #pragma unroll
                for (int j = 0; j < 8; ++j) acc[i][j] += av[i] * bv[j];
        }
        __syncthreads();
    }
    #pragma unroll
    for (int i = 0; i < 8; ++i) {
        int g = g0 + ty * 8 + i;
        float bi = bias[g];
        float4 o0, o1;
        o0.x = gelu_f(acc[i][0] + bi); o0.y = gelu_f(acc[i][1] + bi);
        o0.z = gelu_f(acc[i][2] + bi); o0.w = gelu_f(acc[i][3] + bi);
        o1.x = gelu_f(acc[i][4] + bi); o1.y = gelu_f(acc[i][5] + bi);
        o1.z = gelu_f(acc[i][6] + bi); o1.w = gelu_f(acc[i][7] + bi);
        float* dst = &hbuf[((size_t)b * H_ + g) * L_ + l0 + tx * 8];
        *(float4*)dst = o0;
        *(float4*)(dst + 4) = o1;
    }
}

// ---------------------------------------------------------------- MFMA Toeplitz conv + D*h + BN-stats + FiLM + gelu + residual
// One block per g. Y[b,l] = sum_j H[b,j] K[l-j].  A = H (16xK), B = Toeplitz(K) (Kx16).
// mfma_f32_16x16x32_bf16: A row = lane&15 (=b), B col = lane&15 (=l-off),
// D: col = lane&15, row = (lane>>4)*4 + reg (=b)  [m89-verified layouts].
__global__ __launch_bounds__(512, 4) void k_conv_mfma(
    float* __restrict__ hy, const float* __restrict__ Kbuf,
    const float* __restrict__ Dp, const float* __restrict__ x,
    const float* __restrict__ gb, const float* __restrict__ res_w) {
    int g = blockIdx.x;
    __shared__ u16 Hs[16 * PITCH];     // 65.7 KB, bf16 h rows for all 16 b
    __shared__ u32 KD[2112];           // 8.4 KB: (Krev[i], Krev[i+1]) pairs, zero-padded
    __shared__ float red_s[8], red_q[8], bc[2];
    int t = threadIdx.x;
    int wv = t >> 6, lane = t & 63;
    int n = lane & 15, kg = lane >> 4;

    // --- stage K (reversed + duplicated pairs): Krev[i] = K[2047-i], 0 beyond
    const float* Kg = Kbuf + (size_t)g * L_;
    for (int i = t; i < 2112; i += 512) {
        float a = (i < L_)     ? Kg[L_ - 1 - i] : 0.f;
        float b = (i + 1 < L_) ? Kg[L_ - 2 - i] : 0.f;
        KD[i] = pack2(a, b);
    }
    // --- stage H rows (f32 -> bf16)
    for (int b = 0; b < B_; ++b) {
        const float4 v = *(const float4*)&hy[((size_t)b * H_ + g) * L_ + t * 4];
        u32* dst = (u32*)&Hs[b * PITCH];
        dst[t * 2]     = pack2(v.x, v.y);
        dst[t * 2 + 1] = pack2(v.z, v.w);
    }
    __syncthreads();

    // wave wv owns l-tiles l0 = 16*(8*tt + wv), tt = 0..15 (stride-8: balanced triangle)
    f32x4 acc[16];
    #pragma unroll
    for (int tt = 0; tt < 16; ++tt) acc[tt] = (f32x4){0.f, 0.f, 0.f, 0.f};

    const int qbase = 2047 + kg * 8 - n;      // Krev base, per-lane invariant
    const int jmax = (120 + wv) << 4;         // largest l0 of this wave
    for (int j0 = 0; j0 < L_; j0 += 32) {
        if (j0 > jmax) break;
        bf16x8 af = *(const bf16x8*)&Hs[n * PITCH + j0 + kg * 8];  // A: H[b=n][j0+k]
        #pragma unroll
        for (int tt = 0; tt < 16; ++tt) {
            const int l0 = ((tt << 3) + wv) << 4;
            if (j0 <= l0) {                   // wave-uniform branch
                int base = qbase + j0 - l0;   // = 2047 - d0 - n + kg*8
                union { u32 u[4]; bf16x8 v; } bu;
                bu.u[0] = KD[base];     bu.u[1] = KD[base + 2];
                bu.u[2] = KD[base + 4]; bu.u[3] = KD[base + 6];
                acc[tt] = __builtin_amdgcn_mfma_f32_16x16x32_bf16(af, bu.v, acc[tt], 0, 0, 0);
            }
        }
    }

    // --- epilogue: y = conv + D*h ; per-g stats ; BN + FiLM + gelu + residual
    float Dg = Dp[g];
    float sum = 0.f, sq = 0.f;
    #pragma unroll
    for (int tt = 0; tt < 16; ++tt) {
        const int l0 = ((tt << 3) + wv) << 4;
        #pragma unroll
        for (int r = 0; r < 4; ++r) {
            int b = kg * 4 + r;
            float hval = bf2f(Hs[b * PITCH + l0 + n]);
            float y = acc[tt][r] + Dg * hval;
            acc[tt][r] = y;
            sum += y; sq += y * y;
        }
    }
    #pragma unroll
    for (int off = 32; off > 0; off >>= 1) {
        sum += __shfl_down(sum, off);
        sq  += __shfl_down(sq, off);
    }
    if (lane == 0) { red_s[wv] = sum; red_q[wv] = sq; }
    __syncthreads();
    if (t == 0) {
        float s = 0.f, q = 0.f;
        #pragma unroll
        for (int i = 0; i < 8; ++i) { s += red_s[i]; q += red_q[i]; }
        const float inv = 1.0f / (float)(B_ * L_);
        float mean = s * inv;
        float var = q * inv - mean * mean;
        bc[0] = mean; bc[1] = rsqrtf(var + 1e-5f);
    }
    __syncthreads();
    const float mean = bc[0], rstd = bc[1];
    const float rw = res_w[g];
    #pragma unroll
    for (int r = 0; r < 4; ++r) {
        int b = kg * 4 + r;
        float gf = gb[b * (2 * H_) + g];
        float bb = gb[b * (2 * H_) + H_ + g];
        #pragma unroll
        for (int tt = 0; tt < 16; ++tt) {
            const int l0 = ((tt << 3) + wv) << 4;
            size_t idx = ((size_t)b * H_ + g) * L_ + l0 + n;
            float yn = (acc[tt][r] - mean) * rstd;
            hy[idx] = gelu_f(yn * gf + bb) + x[idx] * rw;
        }
    }
}

// ---------------------------------------------------------------- launch
extern "C" void kernel_launch(void* const* d_in, const int* in_sizes, int n_in,
                              void* d_out, int out_size, void* d_ws, size_t ws_size,
                              hipStream_t stream) {
    const int expect[12] = {16777216, 2048, 262144, 512, 512, 65536,
                            32768, 32768, 512, 131072, 1024, 512};
    bool ok = (n_in == 12);
    if (ok) for (int i = 0; i < 12; ++i) if (in_sizes[i] != expect[i]) ok = false;
    if (!ok) {
        k_fill<<<(out_size + 255) / 256, 256, 0, stream>>>((float*)d_out, out_size, 1000.0f);
        return;
    }
    if (ws_size < ((size_t)H_ * L_ * 4 + (size_t)B_ * 2 * H_ * 4 + 1024)) {
        k_fill<<<(out_size + 255) / 256, 256, 0, stream>>>((float*)d_out, out_size, 2000.0f);
        return;
    }

    const float* x          = (const float*)d_in[0];
    const float* cond       = (const float*)d_in[1];
    const float* linear_w   = (const float*)d_in[2];
    const float* linear_b   = (const float*)d_in[3];
    const float* log_dt     = (const float*)d_in[4];
    const float* C_ri       = (const float*)d_in[5];
    const float* log_A_real = (const float*)d_in[6];
    const float* A_imag     = (const float*)d_in[7];
    const float* Dp         = (const float*)d_in[8];
    const float* film_w     = (const float*)d_in[9];
    const float* film_b     = (const float*)d_in[10];
    const float* res_w      = (const float*)d_in[11];

    float* hy = (float*)d_out;   // h -> final output, f32, B*H*L

    char* w = (char*)d_ws;
    float* Kbuf  = (float*)w;  w += (size_t)H_ * L_ * 4;        // 4 MB
    float* gb    = (float*)w;  w += (size_t)B_ * 2 * H_ * 4;    // 64 KB

    k_compute_K<<<H_, 256, 0, stream>>>(log_dt, C_ri, log_A_real, A_imag, Kbuf);
    k_film<<<(B_ * 2 * H_) / 256, 256, 0, stream>>>(cond, film_w, film_b, gb);
    dim3 gmm(L_ / BLT, H_ / BM, B_);
    k_linear<<<gmm, 256, 0, stream>>>(x, linear_w, linear_b, hy);
    k_conv_mfma<<<H_, 512, 0, stream>>>(hy, Kbuf, Dp, x, gb, res_w);
}

// Round 9
// 287.506 us; speedup vs baseline: 8.5867x; 1.4764x over previous
//
#include <hip/hip_runtime.h>
#include <math.h>

#define B_ 16
#define H_ 512
#define L_ 2048
#define N_ 64
#define CD_ 128
#define PITCH 2052   // bf16 elements per H_lds row in conv (+4 pad)
#define APITCH 40    // bf16 per LDS row in linear tiles (32 + 8 pad -> 80B rows)

typedef unsigned int u32;
typedef unsigned short u16;
typedef __attribute__((ext_vector_type(8))) short bf16x8;   // 8 bf16 in 4 VGPRs
typedef __attribute__((ext_vector_type(4))) float f32x4;    // mfma 16x16x32 C/D

__device__ __forceinline__ float gelu_f(float v) {
    return 0.5f * v * (1.0f + erff(v * 0.70710678118654752f));
}
__device__ __forceinline__ float bf2f(u16 b) {
    union { u32 u; float f; } c; c.u = ((u32)b) << 16; return c.f;
}
__device__ __forceinline__ u16 f2bf(float f) {
    union { float f; u32 u; } c; c.f = f;
    u32 u = c.u;
    return (u16)((u + 0x7FFFu + ((u >> 16) & 1u)) >> 16);
}
__device__ __forceinline__ u32 pack2(float a, float b) {
    return (u32)f2bf(a) | ((u32)f2bf(b) << 16);
}

// ---------------------------------------------------------------- sentinel fill
__global__ void k_fill(float* __restrict__ out, int n, float val) {
    int i = blockIdx.x * 256 + threadIdx.x;
    if (i < n) out[i] = val;
}

// ---------------------------------------------------------------- K (f32 closed form)
__global__ void k_compute_K(const float* __restrict__ log_dt,
                            const float* __restrict__ C_ri,
                            const float* __restrict__ log_A_real,
                            const float* __restrict__ A_imag,
                            float* __restrict__ Kbuf) {
    int h = blockIdx.x;
    __shared__ float dre[N_], dim[N_], cre[N_], cim[N_];
    int t = threadIdx.x;
    if (t < N_) {
        float dt = expf(log_dt[h]);
        float a_re = -expf(log_A_real[h * N_ + t]);
        float a_im = A_imag[h * N_ + t];
        float dA_re = a_re * dt, dA_im = a_im * dt;
        float er = expf(dA_re);
        float s, c;
        sincosf(dA_im, &s, &c);
        float num_re = er * c - 1.0f, num_im = er * s;
        float den = a_re * a_re + a_im * a_im;
        float q_re = (num_re * a_re + num_im * a_im) / den;
        float q_im = (num_im * a_re - num_re * a_im) / den;
        float Cr = C_ri[(h * N_ + t) * 2 + 0];
        float Ci = C_ri[(h * N_ + t) * 2 + 1];
        cre[t] = Cr * q_re - Ci * q_im;
        cim[t] = Cr * q_im + Ci * q_re;
        dre[t] = dA_re; dim[t] = dA_im;
    }
    __syncthreads();
    for (int l = t; l < L_; l += blockDim.x) {
        float fl = (float)l;
        float acc = 0.f;
        for (int n = 0; n < N_; ++n) {
            float er = expf(dre[n] * fl);
            float s, c;
            sincosf(dim[n] * fl, &s, &c);
            acc += er * (cre[n] * c - cim[n] * s);
        }
        Kbuf[(size_t)h * L_ + l] = 2.0f * acc;
    }
}

// ---------------------------------------------------------------- FiLM
__global__ void k_film(const float* __restrict__ cond,
                       const float* __restrict__ film_w,
                       const float* __restrict__ film_b,
                       float* __restrict__ gb) {
    int j = blockIdx.x * 256 + threadIdx.x;   // 0 .. B*2H-1
    int b  = j >> 10;
    int jj = j & 1023;
    float acc = film_b[jj];
    for (int c = 0; c < CD_; ++c)
        acc += cond[b * CD_ + c] * film_w[jj * CD_ + c];
    gb[j] = acc;
}

// ---------------------------------------------------------------- linear via MFMA (bf16) + gelu
// h[b,g,l] = gelu( sum_k W[g,k] x[b,k,l] + bias[g] )
// 128x128 tile, BK=32, 4 waves each owning a 64x64 sub-tile (4x4 fragments).
// A = W[g][k] staged [g_local][APITCH]; B = X^T staged [l_local][APITCH] (k contiguous).
__global__ __launch_bounds__(256) void k_linear_mfma(
    const float* __restrict__ x, const float* __restrict__ W,
    const float* __restrict__ bias, float* __restrict__ hbuf) {
    int b  = blockIdx.z;
    int g0 = blockIdx.y * 128;
    int l0 = blockIdx.x * 128;
    __shared__ u16 Al[128 * APITCH];   // 10.2 KB
    __shared__ u16 Bl[128 * APITCH];   // 10.2 KB
    int t = threadIdx.x;
    int lane = t & 63, wv = t >> 6;
    int n = lane & 15, kg = lane >> 4;
    int wr = wv >> 1, wc = wv & 1;     // wave sub-tile origin (wr*64 g, wc*64 l)

    f32x4 acc[4][4];
    #pragma unroll
    for (int m = 0; m < 4; ++m)
        #pragma unroll
        for (int q = 0; q < 4; ++q) acc[m][q] = (f32x4){0.f, 0.f, 0.f, 0.f};

    for (int k0 = 0; k0 < H_; k0 += 32) {
        // stage A (W): 128 rows x 8 float4, f32 -> bf16
        #pragma unroll
        for (int i = 0; i < 4; ++i) {
            int id = t + 256 * i;            // 0..1023
            int row = id >> 3, f4 = id & 7;
            float4 v = *(const float4*)&W[(size_t)(g0 + row) * H_ + k0 + f4 * 4];
            uint2 p;
            p.x = pack2(v.x, v.y);
            p.y = pack2(v.z, v.w);
            *(uint2*)((char*)Al + row * 80 + f4 * 8) = p;
        }
        // stage B (X^T): 16 k-pairs x 32 l-quads; pack (k, k+1) pairs per l
        #pragma unroll
        for (int i = 0; i < 2; ++i) {
            int id = t + 256 * i;            // 0..511
            int kp = id >> 5, lq = id & 31;
            const float* xp = &x[((size_t)b * H_ + k0 + kp * 2) * L_ + l0 + lq * 4];
            float4 a = *(const float4*)xp;
            float4 c = *(const float4*)(xp + L_);
            ((u32*)((char*)Bl + (lq * 4 + 0) * 80))[kp] = pack2(a.x, c.x);
            ((u32*)((char*)Bl + (lq * 4 + 1) * 80))[kp] = pack2(a.y, c.y);
            ((u32*)((char*)Bl + (lq * 4 + 2) * 80))[kp] = pack2(a.z, c.z);
            ((u32*)((char*)Bl + (lq * 4 + 3) * 80))[kp] = pack2(a.w, c.w);
        }
        __syncthreads();
        bf16x8 af[4], bf[4];
        #pragma unroll
        for (int m = 0; m < 4; ++m)
            af[m] = *(const bf16x8*)((const char*)Al + (wr * 64 + m * 16 + n) * 80 + kg * 16);
        #pragma unroll
        for (int q = 0; q < 4; ++q)
            bf[q] = *(const bf16x8*)((const char*)Bl + (wc * 64 + q * 16 + n) * 80 + kg * 16);
        #pragma unroll
        for (int m = 0; m < 4; ++m)
            #pragma unroll
            for (int q = 0; q < 4; ++q)
                acc[m][q] = __builtin_amdgcn_mfma_f32_16x16x32_bf16(af[m], bf[q], acc[m][q], 0, 0, 0);
        __syncthreads();
    }

    // epilogue: D col = lane&15 (l), row = kg*4 + r (g within fragment)
    #pragma unroll
    for (int m = 0; m < 4; ++m) {
        #pragma unroll
        for (int r = 0; r < 4; ++r) {
            int g = g0 + wr * 64 + m * 16 + kg * 4 + r;
            float bi = bias[g];
            float* dst = &hbuf[((size_t)b * H_ + g) * L_ + l0 + wc * 64 + n];
            #pragma unroll
            for (int q = 0; q < 4; ++q)
                dst[q * 16] = gelu_f(acc[m][q][r] + bi);
        }
    }
}

// ---------------------------------------------------------------- MFMA Toeplitz conv + D*h + BN-stats + FiLM + gelu + residual
__global__ __launch_bounds__(512, 4) void k_conv_mfma(
    float* __restrict__ hy, const float* __restrict__ Kbuf,
    const float* __restrict__ Dp, const float* __restrict__ x,
    const float* __restrict__ gb, const float* __restrict__ res_w) {
    int g = blockIdx.x;
    __shared__ u16 Hs[16 * PITCH];     // 65.7 KB
    __shared__ u32 KD[2112];           // 8.4 KB: (Krev[i], Krev[i+1]) pairs
    __shared__ float red_s[8], red_q[8], bc[2];
    int t = threadIdx.x;
    int wv = t >> 6, lane = t & 63;
    int n = lane & 15, kg = lane >> 4;

    const float* Kg = Kbuf + (size_t)g * L_;
    for (int i = t; i < 2112; i += 512) {
        float a = (i < L_)     ? Kg[L_ - 1 - i] : 0.f;
        float b = (i + 1 < L_) ? Kg[L_ - 2 - i] : 0.f;
        KD[i] = pack2(a, b);
    }
    for (int b = 0; b < B_; ++b) {
        const float4 v = *(const float4*)&hy[((size_t)b * H_ + g) * L_ + t * 4];
        u32* dst = (u32*)&Hs[b * PITCH];
        dst[t * 2]     = pack2(v.x, v.y);
        dst[t * 2 + 1] = pack2(v.z, v.w);
    }
    __syncthreads();

    f32x4 acc[16];
    #pragma unroll
    for (int tt = 0; tt < 16; ++tt) acc[tt] = (f32x4){0.f, 0.f, 0.f, 0.f};

    const int qbase = 2047 + kg * 8 - n;
    const int jmax = (120 + wv) << 4;
    for (int j0 = 0; j0 < L_; j0 += 32) {
        if (j0 > jmax) break;
        bf16x8 af = *(const bf16x8*)&Hs[n * PITCH + j0 + kg * 8];
        #pragma unroll
        for (int tt = 0; tt < 16; ++tt) {
            const int l0 = ((tt << 3) + wv) << 4;
            if (j0 <= l0) {
                int base = qbase + j0 - l0;
                union { u32 u[4]; bf16x8 v; } bu;
                bu.u[0] = KD[base];     bu.u[1] = KD[base + 2];
                bu.u[2] = KD[base + 4]; bu.u[3] = KD[base + 6];
                acc[tt] = __builtin_amdgcn_mfma_f32_16x16x32_bf16(af, bu.v, acc[tt], 0, 0, 0);
            }
        }
    }

    float Dg = Dp[g];
    float sum = 0.f, sq = 0.f;
    #pragma unroll
    for (int tt = 0; tt < 16; ++tt) {
        const int l0 = ((tt << 3) + wv) << 4;
        #pragma unroll
        for (int r = 0; r < 4; ++r) {
            int b = kg * 4 + r;
            float hval = bf2f(Hs[b * PITCH + l0 + n]);
            float y = acc[tt][r] + Dg * hval;
            acc[tt][r] = y;
            sum += y; sq += y * y;
        }
    }
    #pragma unroll
    for (int off = 32; off > 0; off >>= 1) {
        sum += __shfl_down(sum, off);
        sq  += __shfl_down(sq, off);
    }
    if (lane == 0) { red_s[wv] = sum; red_q[wv] = sq; }
    __syncthreads();
    if (t == 0) {
        float s = 0.f, q = 0.f;
        #pragma unroll
        for (int i = 0; i < 8; ++i) { s += red_s[i]; q += red_q[i]; }
        const float inv = 1.0f / (float)(B_ * L_);
        float mean = s * inv;
        float var = q * inv - mean * mean;
        bc[0] = mean; bc[1] = rsqrtf(var + 1e-5f);
    }
    __syncthreads();
    const float mean = bc[0], rstd = bc[1];
    const float rw = res_w[g];
    #pragma unroll
    for (int r = 0; r < 4; ++r) {
        int b = kg * 4 + r;
        float gf = gb[b * (2 * H_) + g];
        float bb = gb[b * (2 * H_) + H_ + g];
        #pragma unroll
        for (int tt = 0; tt < 16; ++tt) {
            const int l0 = ((tt << 3) + wv) << 4;
            size_t idx = ((size_t)b * H_ + g) * L_ + l0 + n;
            float yn = (acc[tt][r] - mean) * rstd;
            hy[idx] = gelu_f(yn * gf + bb) + x[idx] * rw;
        }
    }
}

// ---------------------------------------------------------------- launch
extern "C" void kernel_launch(void* const* d_in, const int* in_sizes, int n_in,
                              void* d_out, int out_size, void* d_ws, size_t ws_size,
                              hipStream_t stream) {
    const int expect[12] = {16777216, 2048, 262144, 512, 512, 65536,
                            32768, 32768, 512, 131072, 1024, 512};
    bool ok = (n_in == 12);
    if (ok) for (int i = 0; i < 12; ++i) if (in_sizes[i] != expect[i]) ok = false;
    if (!ok) {
        k_fill<<<(out_size + 255) / 256, 256, 0, stream>>>((float*)d_out, out_size, 1000.0f);
        return;
    }
    if (ws_size < ((size_t)H_ * L_ * 4 + (size_t)B_ * 2 * H_ * 4 + 1024)) {
        k_fill<<<(out_size + 255) / 256, 256, 0, stream>>>((float*)d_out, out_size, 2000.0f);
        return;
    }

    const float* x          = (const float*)d_in[0];
    const float* cond       = (const float*)d_in[1];
    const float* linear_w   = (const float*)d_in[2];
    const float* linear_b   = (const float*)d_in[3];
    const float* log_dt     = (const float*)d_in[4];
    const float* C_ri       = (const float*)d_in[5];
    const float* log_A_real = (const float*)d_in[6];
    const float* A_imag     = (const float*)d_in[7];
    const float* Dp         = (const float*)d_in[8];
    const float* film_w     = (const float*)d_in[9];
    const float* film_b     = (const float*)d_in[10];
    const float* res_w      = (const float*)d_in[11];

    float* hy = (float*)d_out;   // h -> final output, f32, B*H*L

    char* w = (char*)d_ws;
    float* Kbuf  = (float*)w;  w += (size_t)H_ * L_ * 4;        // 4 MB
    float* gb    = (float*)w;  w += (size_t)B_ * 2 * H_ * 4;    // 64 KB

    k_compute_K<<<H_, 256, 0, stream>>>(log_dt, C_ri, log_A_real, A_imag, Kbuf);
    k_film<<<(B_ * 2 * H_) / 256, 256, 0, stream>>>(cond, film_w, film_b, gb);
    dim3 gmm(L_ / 128, H_ / 128, B_);
    k_linear_mfma<<<gmm, 256, 0, stream>>>(x, linear_w, linear_b, hy);
    k_conv_mfma<<<H_, 512, 0, stream>>>(hy, Kbuf, Dp, x, gb, res_w);
}

// Round 10
// 223.120 us; speedup vs baseline: 11.0646x; 1.2886x over previous
//
#include <hip/hip_runtime.h>
#include <math.h>

#define B_ 16
#define H_ 512
#define L_ 2048
#define N_ 64
#define CD_ 128
#define PITCH 2052   // bf16 elements per H_lds row in conv (+4 pad)
#define WPITCH 264   // u16 per Wp row (256 + 8 pad) -> 528 B

typedef unsigned int u32;
typedef unsigned short u16;
typedef __attribute__((ext_vector_type(8))) short bf16x8;   // 8 bf16 in 4 VGPRs
typedef __attribute__((ext_vector_type(4))) float f32x4;    // mfma 16x16x32 C/D

__device__ __forceinline__ float gelu_f(float v) {
    return 0.5f * v * (1.0f + erff(v * 0.70710678118654752f));
}
__device__ __forceinline__ float bf2f(u16 b) {
    union { u32 u; float f; } c; c.u = ((u32)b) << 16; return c.f;
}
__device__ __forceinline__ u16 f2bf(float f) {
    union { float f; u32 u; } c; c.f = f;
    u32 u = c.u;
    return (u16)((u + 0x7FFFu + ((u >> 16) & 1u)) >> 16);
}
__device__ __forceinline__ u32 pack2(float a, float b) {
    return (u32)f2bf(a) | ((u32)f2bf(b) << 16);
}

// ---------------------------------------------------------------- sentinel fill
__global__ void k_fill(float* __restrict__ out, int n, float val) {
    int i = blockIdx.x * 256 + threadIdx.x;
    if (i < n) out[i] = val;
}

// ---------------------------------------------------------------- K via tables
// K[h][l] = 2*Re( sum_n Cm_n exp(dtA_n*l) ); l = 32q + r;
// Thi[n][q] = Cm_n*exp(dtA_n*32q), Elo[n][r] = exp(dtA_n*r). 16x fewer sincosf.
__global__ __launch_bounds__(256) void k_K3(
    const float* __restrict__ log_dt, const float* __restrict__ C_ri,
    const float* __restrict__ log_A_real, const float* __restrict__ A_imag,
    float* __restrict__ Kbuf) {
    int h = blockIdx.x;
    int t = threadIdx.x;
    __shared__ float dre[N_], dim[N_], cre[N_], cim[N_];
    __shared__ float2 Thi[64 * 64];   // 32 KB
    __shared__ float2 Elo[64 * 32];   // 16 KB
    if (t < N_) {
        float dt = expf(log_dt[h]);
        float a_re = -expf(log_A_real[h * N_ + t]);
        float a_im = A_imag[h * N_ + t];
        float dA_re = a_re * dt, dA_im = a_im * dt;
        float er = expf(dA_re);
        float s, c;
        sincosf(dA_im, &s, &c);
        float num_re = er * c - 1.0f, num_im = er * s;
        float den = a_re * a_re + a_im * a_im;
        float q_re = (num_re * a_re + num_im * a_im) / den;
        float q_im = (num_im * a_re - num_re * a_im) / den;
        float Cr = C_ri[(h * N_ + t) * 2 + 0];
        float Ci = C_ri[(h * N_ + t) * 2 + 1];
        cre[t] = Cr * q_re - Ci * q_im;
        cim[t] = Cr * q_im + Ci * q_re;
        dre[t] = dA_re; dim[t] = dA_im;
    }
    __syncthreads();
    #pragma unroll
    for (int i = 0; i < 16; ++i) {      // Thi: 4096 entries
        int id = t + 256 * i;
        int n = id >> 6, q = id & 63;
        float a = (float)(32 * q);
        float er = expf(dre[n] * a);
        float s, c;
        sincosf(dim[n] * a, &s, &c);
        Thi[id] = make_float2(er * (cre[n] * c - cim[n] * s),
                              er * (cre[n] * s + cim[n] * c));
    }
    #pragma unroll
    for (int i = 0; i < 8; ++i) {       // Elo: 2048 entries
        int id = t + 256 * i;
        int n = id >> 5, r = id & 31;
        float a = (float)r;
        float er = expf(dre[n] * a);
        float s, c;
        sincosf(dim[n] * a, &s, &c);
        Elo[id] = make_float2(er * c, er * s);
    }
    __syncthreads();
    // thread t covers l = 8t..8t+7 : q = t>>2 (const), r = 8*(t&3)+j
    int q = t >> 2, r0 = (t & 3) * 8;
    float acc[8] = {};
    for (int n = 0; n < 64; ++n) {
        float2 T = Thi[n * 64 + q];                 // 4-lane broadcast
        const float2* e = &Elo[n * 32 + r0];        // 64B contiguous
        #pragma unroll
        for (int j = 0; j < 8; ++j)
            acc[j] += T.x * e[j].x - T.y * e[j].y;  // Re(Thi*Elo)
    }
    float* out = Kbuf + (size_t)h * L_ + t * 8;
    #pragma unroll
    for (int j = 0; j < 8; ++j) out[j] = 2.0f * acc[j];
}

// ---------------------------------------------------------------- FiLM
__global__ void k_film(const float* __restrict__ cond,
                       const float* __restrict__ film_w,
                       const float* __restrict__ film_b,
                       float* __restrict__ gb) {
    int j = blockIdx.x * 256 + threadIdx.x;   // 0 .. B*2H-1
    int b  = j >> 10;
    int jj = j & 1023;
    float acc = film_b[jj];
    for (int c = 0; c < CD_; ++c)
        acc += cond[b * CD_ + c] * film_w[jj * CD_ + c];
    gb[j] = acc;
}

// ---------------------------------------------------------------- linear v3: resident W half-panels
// h[b,g,l] = gelu( sum_k W[g,k] x[b,k,l] + bias[g] )
// 512 thr / 8 waves; wave (wr,wc) owns 32g x 32l? -> wr in {0,1} x 64g? see below:
// wave wv: wr=wv>>2 (2), wc=wv&3 (4); owns g in [wr*64, wr*64+64) x l in [wc*32, +32).
__global__ __launch_bounds__(512, 2) void k_linear3(
    const float* __restrict__ x, const float* __restrict__ W,
    const float* __restrict__ bias, float* __restrict__ hbuf) {
    int b  = blockIdx.z;
    int g0 = blockIdx.y * 128;
    int l0 = blockIdx.x * 128;
    __shared__ u16 Wp[128 * WPITCH];   // 67.6 KB : W panel [128 g][256 k] bf16
    __shared__ u16 Bl[128 * 40];       // 10.2 KB : x^T tile [128 l][32 k] bf16
    int t = threadIdx.x;
    int lane = t & 63, wv = t >> 6;
    int n = lane & 15, kg = lane >> 4;
    int wr = wv >> 2, wc = wv & 3;
    int kp = t >> 5, lq = t & 31;      // B-staging roles

    f32x4 acc[4][2];
    #pragma unroll
    for (int m = 0; m < 4; ++m)
        #pragma unroll
        for (int q = 0; q < 2; ++q) acc[m][q] = (f32x4){0.f, 0.f, 0.f, 0.f};

    const float* xb = x + (size_t)b * H_ * L_ + l0;
    // prefetch ks=0 x rows
    float4 pa = *(const float4*)&xb[(size_t)(2 * kp) * L_ + lq * 4];
    float4 pc = *(const float4*)&xb[(size_t)(2 * kp + 1) * L_ + lq * 4];

    for (int half = 0; half < 2; ++half) {
        // stage W half-panel [128 g][256 k] (all waves participate; visible after barrier B)
        #pragma unroll
        for (int i = 0; i < 16; ++i) {
            int f = t + 512 * i;               // 0..8191 float4s
            int row = f >> 6, c4 = f & 63;
            float4 v = *(const float4*)&W[(size_t)(g0 + row) * H_ + half * 256 + c4 * 4];
            uint2 pw;
            pw.x = pack2(v.x, v.y);
            pw.y = pack2(v.z, v.w);
            *(uint2*)((char*)Wp + row * (WPITCH * 2) + c4 * 8) = pw;
        }
        for (int ks8 = 0; ks8 < 8; ++ks8) {
            int ks = half * 8 + ks8;
            __syncthreads();   // barrier A: prev-iter frag reads (and W reads) done
            // write prefetched x into Bl (transposed, k-contiguous rows)
            ((u32*)((char*)Bl + (lq * 4 + 0) * 80))[kp] = pack2(pa.x, pc.x);
            ((u32*)((char*)Bl + (lq * 4 + 1) * 80))[kp] = pack2(pa.y, pc.y);
            ((u32*)((char*)Bl + (lq * 4 + 2) * 80))[kp] = pack2(pa.z, pc.z);
            ((u32*)((char*)Bl + (lq * 4 + 3) * 80))[kp] = pack2(pa.w, pc.w);
            __syncthreads();   // barrier B: Bl (+ Wp at ks8==0) ready
            // prefetch next k-step
            if (ks < 15) {
                int kn = (ks + 1) * 32;
                pa = *(const float4*)&xb[(size_t)(kn + 2 * kp) * L_ + lq * 4];
                pc = *(const float4*)&xb[(size_t)(kn + 2 * kp + 1) * L_ + lq * 4];
            }
            // fragments + MFMA
            bf16x8 af[4], bf[2];
            #pragma unroll
            for (int m = 0; m < 4; ++m)
                af[m] = *(const bf16x8*)((const char*)Wp +
                        (wr * 64 + m * 16 + n) * (WPITCH * 2) + ks8 * 64 + kg * 16);
            #pragma unroll
            for (int q = 0; q < 2; ++q)
                bf[q] = *(const bf16x8*)((const char*)Bl +
                        (wc * 32 + q * 16 + n) * 80 + kg * 16);
            #pragma unroll
            for (int m = 0; m < 4; ++m)
                #pragma unroll
                for (int q = 0; q < 2; ++q)
                    acc[m][q] = __builtin_amdgcn_mfma_f32_16x16x32_bf16(
                        af[m], bf[q], acc[m][q], 0, 0, 0);
        }
        __syncthreads();   // done reading Wp(half) before restage
    }

    // epilogue: D col = n (l), row = kg*4 + r (g)
    #pragma unroll
    for (int m = 0; m < 4; ++m) {
        #pragma unroll
        for (int r = 0; r < 4; ++r) {
            int g = g0 + wr * 64 + m * 16 + kg * 4 + r;
            float bi = bias[g];
            float* dst = &hbuf[((size_t)b * H_ + g) * L_ + l0 + wc * 32 + n];
            #pragma unroll
            for (int q = 0; q < 2; ++q)
                dst[q * 16] = gelu_f(acc[m][q][r] + bi);
        }
    }
}

// ---------------------------------------------------------------- MFMA Toeplitz conv + D*h + BN-stats + FiLM + gelu + residual
__global__ __launch_bounds__(512, 4) void k_conv_mfma(
    float* __restrict__ hy, const float* __restrict__ Kbuf,
    const float* __restrict__ Dp, const float* __restrict__ x,
    const float* __restrict__ gb, const float* __restrict__ res_w) {
    int g = blockIdx.x;
    __shared__ u16 Hs[16 * PITCH];     // 65.7 KB
    __shared__ u32 KD[2112];           // 8.4 KB: (Krev[i], Krev[i+1]) pairs
    __shared__ float red_s[8], red_q[8], bc[2];
    int t = threadIdx.x;
    int wv = t >> 6, lane = t & 63;
    int n = lane & 15, kg = lane >> 4;

    const float* Kg = Kbuf + (size_t)g * L_;
    for (int i = t; i < 2112; i += 512) {
        float a = (i < L_)     ? Kg[L_ - 1 - i] : 0.f;
        float b = (i + 1 < L_) ? Kg[L_ - 2 - i] : 0.f;
        KD[i] = pack2(a, b);
    }
    for (int b = 0; b < B_; ++b) {
        const float4 v = *(const float4*)&hy[((size_t)b * H_ + g) * L_ + t * 4];
        u32* dst = (u32*)&Hs[b * PITCH];
        dst[t * 2]     = pack2(v.x, v.y);
        dst[t * 2 + 1] = pack2(v.z, v.w);
    }
    __syncthreads();

    f32x4 acc[16];
    #pragma unroll
    for (int tt = 0; tt < 16; ++tt) acc[tt] = (f32x4){0.f, 0.f, 0.f, 0.f};

    const int qbase = 2047 + kg * 8 - n;
    const int jmax = (120 + wv) << 4;
    for (int j0 = 0; j0 < L_; j0 += 32) {
        if (j0 > jmax) break;
        bf16x8 af = *(const bf16x8*)&Hs[n * PITCH + j0 + kg * 8];
        #pragma unroll
        for (int tt = 0; tt < 16; ++tt) {
            const int l0 = ((tt << 3) + wv) << 4;
            if (j0 <= l0) {
                int base = qbase + j0 - l0;
                union { u32 u[4]; bf16x8 v; } bu;
                bu.u[0] = KD[base];     bu.u[1] = KD[base + 2];
                bu.u[2] = KD[base + 4]; bu.u[3] = KD[base + 6];
                acc[tt] = __builtin_amdgcn_mfma_f32_16x16x32_bf16(af, bu.v, acc[tt], 0, 0, 0);
            }
        }
    }

    float Dg = Dp[g];
    float sum = 0.f, sq = 0.f;
    #pragma unroll
    for (int tt = 0; tt < 16; ++tt) {
        const int l0 = ((tt << 3) + wv) << 4;
        #pragma unroll
        for (int r = 0; r < 4; ++r) {
            int b = kg * 4 + r;
            float hval = bf2f(Hs[b * PITCH + l0 + n]);
            float y = acc[tt][r] + Dg * hval;
            acc[tt][r] = y;
            sum += y; sq += y * y;
        }
    }
    #pragma unroll
    for (int off = 32; off > 0; off >>= 1) {
        sum += __shfl_down(sum, off);
        sq  += __shfl_down(sq, off);
    }
    if (lane == 0) { red_s[wv] = sum; red_q[wv] = sq; }
    __syncthreads();
    if (t == 0) {
        float s = 0.f, q = 0.f;
        #pragma unroll
        for (int i = 0; i < 8; ++i) { s += red_s[i]; q += red_q[i]; }
        const float inv = 1.0f / (float)(B_ * L_);
        float mean = s * inv;
        float var = q * inv - mean * mean;
        bc[0] = mean; bc[1] = rsqrtf(var + 1e-5f);
    }
    __syncthreads();
    const float mean = bc[0], rstd = bc[1];
    const float rw = res_w[g];
    #pragma unroll
    for (int r = 0; r < 4; ++r) {
        int b = kg * 4 + r;
        float gf = gb[b * (2 * H_) + g];
        float bb = gb[b * (2 * H_) + H_ + g];
        #pragma unroll
        for (int tt = 0; tt < 16; ++tt) {
            const int l0 = ((tt << 3) + wv) << 4;
            size_t idx = ((size_t)b * H_ + g) * L_ + l0 + n;
            float yn = (acc[tt][r] - mean) * rstd;
            hy[idx] = gelu_f(yn * gf + bb) + x[idx] * rw;
        }
    }
}

// ---------------------------------------------------------------- launch
extern "C" void kernel_launch(void* const* d_in, const int* in_sizes, int n_in,
                              void* d_out, int out_size, void* d_ws, size_t ws_size,
                              hipStream_t stream) {
    const int expect[12] = {16777216, 2048, 262144, 512, 512, 65536,
                            32768, 32768, 512, 131072, 1024, 512};
    bool ok = (n_in == 12);
    if (ok) for (int i = 0; i < 12; ++i) if (in_sizes[i] != expect[i]) ok = false;
    if (!ok) {
        k_fill<<<(out_size + 255) / 256, 256, 0, stream>>>((float*)d_out, out_size, 1000.0f);
        return;
    }
    if (ws_size < ((size_t)H_ * L_ * 4 + (size_t)B_ * 2 * H_ * 4 + 1024)) {
        k_fill<<<(out_size + 255) / 256, 256, 0, stream>>>((float*)d_out, out_size, 2000.0f);
        return;
    }

    const float* x          = (const float*)d_in[0];
    const float* cond       = (const float*)d_in[1];
    const float* linear_w   = (const float*)d_in[2];
    const float* linear_b   = (const float*)d_in[3];
    const float* log_dt     = (const float*)d_in[4];
    const float* C_ri       = (const float*)d_in[5];
    const float* log_A_real = (const float*)d_in[6];
    const float* A_imag     = (const float*)d_in[7];
    const float* Dp         = (const float*)d_in[8];
    const float* film_w     = (const float*)d_in[9];
    const float* film_b     = (const float*)d_in[10];
    const float* res_w      = (const float*)d_in[11];

    float* hy = (float*)d_out;   // h -> final output, f32, B*H*L

    char* w = (char*)d_ws;
    float* Kbuf  = (float*)w;  w += (size_t)H_ * L_ * 4;        // 4 MB
    float* gb    = (float*)w;  w += (size_t)B_ * 2 * H_ * 4;    // 64 KB

    k_K3<<<H_, 256, 0, stream>>>(log_dt, C_ri, log_A_real, A_imag, Kbuf);
    k_film<<<(B_ * 2 * H_) / 256, 256, 0, stream>>>(cond, film_w, film_b, gb);
    dim3 gmm(L_ / 128, H_ / 128, B_);
    k_linear3<<<gmm, 512, 0, stream>>>(x, linear_w, linear_b, hy);
    k_conv_mfma<<<H_, 512, 0, stream>>>(hy, Kbuf, Dp, x, gb, res_w);
}

// Round 11
// 174.796 us; speedup vs baseline: 14.1234x; 1.2765x over previous
//
#include <hip/hip_runtime.h>
#include <math.h>

#define B_ 16
#define H_ 512
#define L_ 2048
#define N_ 64
#define CD_ 128
#define PITCH 2052   // bf16 elements per H_lds row in conv (+4 pad)

typedef unsigned int u32;
typedef unsigned short u16;
typedef __attribute__((ext_vector_type(8))) short bf16x8;   // 8 bf16 in 4 VGPRs
typedef __attribute__((ext_vector_type(4))) float f32x4;    // mfma 16x16x32 C/D

__device__ __forceinline__ float gelu_f(float v) {
    return 0.5f * v * (1.0f + erff(v * 0.70710678118654752f));
}
__device__ __forceinline__ float bf2f(u16 b) {
    union { u32 u; float f; } c; c.u = ((u32)b) << 16; return c.f;
}
__device__ __forceinline__ u16 f2bf(float f) {
    union { float f; u32 u; } c; c.f = f;
    u32 u = c.u;
    return (u16)((u + 0x7FFFu + ((u >> 16) & 1u)) >> 16);
}
__device__ __forceinline__ u32 pack2(float a, float b) {
    return (u32)f2bf(a) | ((u32)f2bf(b) << 16);
}

// ---------------------------------------------------------------- sentinel fill
__global__ void k_fill(float* __restrict__ out, int n, float val) {
    int i = blockIdx.x * 256 + threadIdx.x;
    if (i < n) out[i] = val;
}

// ---------------------------------------------------------------- K via tables
__global__ __launch_bounds__(256) void k_K3(
    const float* __restrict__ log_dt, const float* __restrict__ C_ri,
    const float* __restrict__ log_A_real, const float* __restrict__ A_imag,
    float* __restrict__ Kbuf) {
    int h = blockIdx.x;
    int t = threadIdx.x;
    __shared__ float dre[N_], dim[N_], cre[N_], cim[N_];
    __shared__ float2 Thi[64 * 64];   // 32 KB
    __shared__ float2 Elo[64 * 32];   // 16 KB
    if (t < N_) {
        float dt = expf(log_dt[h]);
        float a_re = -expf(log_A_real[h * N_ + t]);
        float a_im = A_imag[h * N_ + t];
        float dA_re = a_re * dt, dA_im = a_im * dt;
        float er = expf(dA_re);
        float s, c;
        sincosf(dA_im, &s, &c);
        float num_re = er * c - 1.0f, num_im = er * s;
        float den = a_re * a_re + a_im * a_im;
        float q_re = (num_re * a_re + num_im * a_im) / den;
        float q_im = (num_im * a_re - num_re * a_im) / den;
        float Cr = C_ri[(h * N_ + t) * 2 + 0];
        float Ci = C_ri[(h * N_ + t) * 2 + 1];
        cre[t] = Cr * q_re - Ci * q_im;
        cim[t] = Cr * q_im + Ci * q_re;
        dre[t] = dA_re; dim[t] = dA_im;
    }
    __syncthreads();
    #pragma unroll
    for (int i = 0; i < 16; ++i) {
        int id = t + 256 * i;
        int n = id >> 6, q = id & 63;
        float a = (float)(32 * q);
        float er = expf(dre[n] * a);
        float s, c;
        sincosf(dim[n] * a, &s, &c);
        Thi[id] = make_float2(er * (cre[n] * c - cim[n] * s),
                              er * (cre[n] * s + cim[n] * c));
    }
    #pragma unroll
    for (int i = 0; i < 8; ++i) {
        int id = t + 256 * i;
        int n = id >> 5, r = id & 31;
        float a = (float)r;
        float er = expf(dre[n] * a);
        float s, c;
        sincosf(dim[n] * a, &s, &c);
        Elo[id] = make_float2(er * c, er * s);
    }
    __syncthreads();
    int q = t >> 2, r0 = (t & 3) * 8;
    float acc[8] = {};
    for (int n = 0; n < 64; ++n) {
        float2 T = Thi[n * 64 + q];
        const float2* e = &Elo[n * 32 + r0];
        #pragma unroll
        for (int j = 0; j < 8; ++j)
            acc[j] += T.x * e[j].x - T.y * e[j].y;
    }
    float* out = Kbuf + (size_t)h * L_ + t * 8;
    #pragma unroll
    for (int j = 0; j < 8; ++j) out[j] = 2.0f * acc[j];
}

// ---------------------------------------------------------------- FiLM
__global__ void k_film(const float* __restrict__ cond,
                       const float* __restrict__ film_w,
                       const float* __restrict__ film_b,
                       float* __restrict__ gb) {
    int j = blockIdx.x * 256 + threadIdx.x;
    int b  = j >> 10;
    int jj = j & 1023;
    float acc = film_b[jj];
    for (int c = 0; c < CD_; ++c)
        acc += cond[b * CD_ + c] * film_w[jj * CD_ + c];
    gb[j] = acc;
}

// ---------------------------------------------------------------- linear v4: BK=64, swizzled Wp, deep prefetch
// h[b,g,l] = gelu( sum_k W[g,k] x[b,k,l] + bias[g] )
// 512 thr / 8 waves; tile 128g x 128l; wave (wr=wv>>2, wc=wv&3) owns 64g x 32l.
__global__ __launch_bounds__(512, 4) void k_linear4(
    const float* __restrict__ x, const float* __restrict__ W,
    const float* __restrict__ bias, float* __restrict__ hbuf) {
    int b  = blockIdx.z;
    int g0 = blockIdx.y * 128;
    int l0 = blockIdx.x * 128;
    __shared__ __align__(16) u16 Wp[128 * 64];   // 16 KB, swizzled rows of 128 B
    __shared__ __align__(16) u16 Bl[128 * 72];   // 18 KB, rows of 144 B (64k + 8 pad)
    int t = threadIdx.x;
    int lane = t & 63, wv = t >> 6;
    int n = lane & 15, kg = lane >> 4;
    int wr = wv >> 2, wc = wv & 3;
    // staging roles
    int lr  = t & 127, kq = t >> 7;   // x: l-row lr, k-base kq*16
    int rw  = (t >> 4) & 31;          // W: rows rw + 32e
    int f16 = t & 15;                 // W: float4-col (k = f16*4..+3)

    f32x4 acc[4][2];
    #pragma unroll
    for (int m = 0; m < 4; ++m)
        #pragma unroll
        for (int q = 0; q < 2; ++q) acc[m][q] = (f32x4){0.f, 0.f, 0.f, 0.f};

    const float* xcol = x + (size_t)b * H_ * L_ + l0 + lr;
    float  cx[16], nx[16];
    float4 cw[4],  nw[4];
    #pragma unroll
    for (int e = 0; e < 16; ++e) cx[e] = xcol[(size_t)(kq * 16 + e) * L_];
    #pragma unroll
    for (int e = 0; e < 4; ++e)
        cw[e] = *(const float4*)&W[(size_t)(g0 + rw + 32 * e) * H_ + f16 * 4];

    #pragma unroll
    for (int S = 0; S < 8; ++S) {
        if (S) __syncthreads();            // barrier A: prev frag reads done
        // --- write Bl: 2 x uint4 at row lr, bytes kq*32 (+16)
        {
            u32 px[8];
            #pragma unroll
            for (int e = 0; e < 8; ++e) px[e] = pack2(cx[2 * e], cx[2 * e + 1]);
            uint4 u0 = {px[0], px[1], px[2], px[3]};
            uint4 u1 = {px[4], px[5], px[6], px[7]};
            *(uint4*)((char*)Bl + lr * 144 + kq * 32)      = u0;
            *(uint4*)((char*)Bl + lr * 144 + kq * 32 + 16) = u1;
        }
        // --- write Wp: 4 x uint2, XOR-swizzled within 128-B row
        #pragma unroll
        for (int e = 0; e < 4; ++e) {
            int row = rw + 32 * e;
            uint2 pw;
            pw.x = pack2(cw[e].x, cw[e].y);
            pw.y = pack2(cw[e].z, cw[e].w);
            *(uint2*)((char*)Wp + row * 128 + ((f16 * 8) ^ ((row & 7) << 4))) = pw;
        }
        __syncthreads();                   // barrier B: tiles ready
        if (S < 7) {                       // prefetch next step (hidden under MFMA)
            int k0n = (S + 1) * 64;
            #pragma unroll
            for (int e = 0; e < 16; ++e) nx[e] = xcol[(size_t)(k0n + kq * 16 + e) * L_];
            #pragma unroll
            for (int e = 0; e < 4; ++e)
                nw[e] = *(const float4*)&W[(size_t)(g0 + rw + 32 * e) * H_ + k0n + f16 * 4];
        }
        #pragma unroll
        for (int ks = 0; ks < 2; ++ks) {
            bf16x8 af[4], bfr[2];
            #pragma unroll
            for (int m = 0; m < 4; ++m) {
                int row = wr * 64 + m * 16 + n;
                af[m] = *(const bf16x8*)((const char*)Wp + row * 128 +
                         ((ks * 64 + kg * 16) ^ ((n & 7) << 4)));
            }
            #pragma unroll
            for (int q = 0; q < 2; ++q)
                bfr[q] = *(const bf16x8*)((const char*)Bl +
                          (wc * 32 + q * 16 + n) * 144 + ks * 64 + kg * 16);
            #pragma unroll
            for (int m = 0; m < 4; ++m)
                #pragma unroll
                for (int q = 0; q < 2; ++q)
                    acc[m][q] = __builtin_amdgcn_mfma_f32_16x16x32_bf16(
                        af[m], bfr[q], acc[m][q], 0, 0, 0);
        }
        if (S < 7) {
            #pragma unroll
            for (int e = 0; e < 16; ++e) cx[e] = nx[e];
            #pragma unroll
            for (int e = 0; e < 4; ++e)  cw[e] = nw[e];
        }
    }

    // epilogue: D col = n (l), row = kg*4 + r (g)
    #pragma unroll
    for (int m = 0; m < 4; ++m) {
        #pragma unroll
        for (int r = 0; r < 4; ++r) {
            int g = g0 + wr * 64 + m * 16 + kg * 4 + r;
            float bi = bias[g];
            float* dst = &hbuf[((size_t)b * H_ + g) * L_ + l0 + wc * 32 + n];
            #pragma unroll
            for (int q = 0; q < 2; ++q)
                dst[q * 16] = gelu_f(acc[m][q][r] + bi);
        }
    }
}

// ---------------------------------------------------------------- MFMA Toeplitz conv + D*h + BN-stats + FiLM + gelu + residual
__global__ __launch_bounds__(512, 4) void k_conv_mfma(
    float* __restrict__ hy, const float* __restrict__ Kbuf,
    const float* __restrict__ Dp, const float* __restrict__ x,
    const float* __restrict__ gb, const float* __restrict__ res_w) {
    int g = blockIdx.x;
    __shared__ u16 Hs[16 * PITCH];     // 65.7 KB
    __shared__ u32 KD[2112];           // 8.4 KB: (Krev[i], Krev[i+1]) pairs
    __shared__ float red_s[8], red_q[8], bc[2];
    int t = threadIdx.x;
    int wv = t >> 6, lane = t & 63;
    int n = lane & 15, kg = lane >> 4;

    const float* Kg = Kbuf + (size_t)g * L_;
    for (int i = t; i < 2112; i += 512) {
        float a = (i < L_)     ? Kg[L_ - 1 - i] : 0.f;
        float b = (i + 1 < L_) ? Kg[L_ - 2 - i] : 0.f;
        KD[i] = pack2(a, b);
    }
    for (int b = 0; b < B_; ++b) {
        const float4 v = *(const float4*)&hy[((size_t)b * H_ + g) * L_ + t * 4];
        u32* dst = (u32*)&Hs[b * PITCH];
        dst[t * 2]     = pack2(v.x, v.y);
        dst[t * 2 + 1] = pack2(v.z, v.w);
    }
    __syncthreads();

    f32x4 acc[16];
    #pragma unroll
    for (int tt = 0; tt < 16; ++tt) acc[tt] = (f32x4){0.f, 0.f, 0.f, 0.f};

    const int qbase = 2047 + kg * 8 - n;
    const int jmax = (120 + wv) << 4;
    for (int j0 = 0; j0 < L_; j0 += 32) {
        if (j0 > jmax) break;
        bf16x8 af = *(const bf16x8*)&Hs[n * PITCH + j0 + kg * 8];
        #pragma unroll
        for (int tt = 0; tt < 16; ++tt) {
            const int l0 = ((tt << 3) + wv) << 4;
            if (j0 <= l0) {
                int base = qbase + j0 - l0;
                union { u32 u[4]; bf16x8 v; } bu;
                bu.u[0] = KD[base];     bu.u[1] = KD[base + 2];
                bu.u[2] = KD[base + 4]; bu.u[3] = KD[base + 6];
                acc[tt] = __builtin_amdgcn_mfma_f32_16x16x32_bf16(af, bu.v, acc[tt], 0, 0, 0);
            }
        }
    }

    float Dg = Dp[g];
    float sum = 0.f, sq = 0.f;
    #pragma unroll
    for (int tt = 0; tt < 16; ++tt) {
        const int l0 = ((tt << 3) + wv) << 4;
        #pragma unroll
        for (int r = 0; r < 4; ++r) {
            int b = kg * 4 + r;
            float hval = bf2f(Hs[b * PITCH + l0 + n]);
            float y = acc[tt][r] + Dg * hval;
            acc[tt][r] = y;
            sum += y; sq += y * y;
        }
    }
    #pragma unroll
    for (int off = 32; off > 0; off >>= 1) {
        sum += __shfl_down(sum, off);
        sq  += __shfl_down(sq, off);
    }
    if (lane == 0) { red_s[wv] = sum; red_q[wv] = sq; }
    __syncthreads();
    if (t == 0) {
        float s = 0.f, q = 0.f;
        #pragma unroll
        for (int i = 0; i < 8; ++i) { s += red_s[i]; q += red_q[i]; }
        const float inv = 1.0f / (float)(B_ * L_);
        float mean = s * inv;
        float var = q * inv - mean * mean;
        bc[0] = mean; bc[1] = rsqrtf(var + 1e-5f);
    }
    __syncthreads();
    const float mean = bc[0], rstd = bc[1];
    const float rw = res_w[g];
    #pragma unroll
    for (int r = 0; r < 4; ++r) {
        int b = kg * 4 + r;
        float gf = gb[b * (2 * H_) + g];
        float bb = gb[b * (2 * H_) + H_ + g];
        #pragma unroll
        for (int tt = 0; tt < 16; ++tt) {
            const int l0 = ((tt << 3) + wv) << 4;
            size_t idx = ((size_t)b * H_ + g) * L_ + l0 + n;
            float yn = (acc[tt][r] - mean) * rstd;
            hy[idx] = gelu_f(yn * gf + bb) + x[idx] * rw;
        }
    }
}

// ---------------------------------------------------------------- launch
extern "C" void kernel_launch(void* const* d_in, const int* in_sizes, int n_in,
                              void* d_out, int out_size, void* d_ws, size_t ws_size,
                              hipStream_t stream) {
    const int expect[12] = {16777216, 2048, 262144, 512, 512, 65536,
                            32768, 32768, 512, 131072, 1024, 512};
    bool ok = (n_in == 12);
    if (ok) for (int i = 0; i < 12; ++i) if (in_sizes[i] != expect[i]) ok = false;
    if (!ok) {
        k_fill<<<(out_size + 255) / 256, 256, 0, stream>>>((float*)d_out, out_size, 1000.0f);
        return;
    }
    if (ws_size < ((size_t)H_ * L_ * 4 + (size_t)B_ * 2 * H_ * 4 + 1024)) {
        k_fill<<<(out_size + 255) / 256, 256, 0, stream>>>((float*)d_out, out_size, 2000.0f);
        return;
    }

    const float* x          = (const float*)d_in[0];
    const float* cond       = (const float*)d_in[1];
    const float* linear_w   = (const float*)d_in[2];
    const float* linear_b   = (const float*)d_in[3];
    const float* log_dt     = (const float*)d_in[4];
    const float* C_ri       = (const float*)d_in[5];
    const float* log_A_real = (const float*)d_in[6];
    const float* A_imag     = (const float*)d_in[7];
    const float* Dp         = (const float*)d_in[8];
    const float* film_w     = (const float*)d_in[9];
    const float* film_b     = (const float*)d_in[10];
    const float* res_w      = (const float*)d_in[11];

    float* hy = (float*)d_out;   // h -> final output, f32, B*H*L

    char* w = (char*)d_ws;
    float* Kbuf  = (float*)w;  w += (size_t)H_ * L_ * 4;        // 4 MB
    float* gb    = (float*)w;  w += (size_t)B_ * 2 * H_ * 4;    // 64 KB

    k_K3<<<H_, 256, 0, stream>>>(log_dt, C_ri, log_A_real, A_imag, Kbuf);
    k_film<<<(B_ * 2 * H_) / 256, 256, 0, stream>>>(cond, film_w, film_b, gb);
    dim3 gmm(L_ / 128, H_ / 128, B_);
    k_linear4<<<gmm, 512, 0, stream>>>(x, linear_w, linear_b, hy);
    k_conv_mfma<<<H_, 512, 0, stream>>>(hy, Kbuf, Dp, x, gb, res_w);
}

// Round 12
// 148.231 us; speedup vs baseline: 16.6546x; 1.1792x over previous
//
#include <hip/hip_runtime.h>
#include <math.h>

#define B_ 16
#define H_ 512
#define L_ 2048
#define N_ 64
#define CD_ 128

typedef unsigned int u32;
typedef unsigned short u16;
typedef __attribute__((ext_vector_type(8))) short bf16x8;   // 8 bf16 in 4 VGPRs
typedef __attribute__((ext_vector_type(4))) float f32x4;    // mfma 16x16x32 C/D

__device__ __forceinline__ float gelu_f(float v) {
    return 0.5f * v * (1.0f + erff(v * 0.70710678118654752f));
}
__device__ __forceinline__ float bf2f(u16 b) {
    union { u32 u; float f; } c; c.u = ((u32)b) << 16; return c.f;
}
__device__ __forceinline__ u16 f2bf(float f) {
    union { float f; u32 u; } c; c.f = f;
    u32 u = c.u;
    return (u16)((u + 0x7FFFu + ((u >> 16) & 1u)) >> 16);
}
__device__ __forceinline__ u32 pack2(float a, float b) {
    return (u32)f2bf(a) | ((u32)f2bf(b) << 16);
}

// ---------------------------------------------------------------- sentinel fill
__global__ void k_fill(float* __restrict__ out, int n, float val) {
    int i = blockIdx.x * 256 + threadIdx.x;
    if (i < n) out[i] = val;
}

// ---------------------------------------------------------------- K via tables
__global__ __launch_bounds__(256) void k_K3(
    const float* __restrict__ log_dt, const float* __restrict__ C_ri,
    const float* __restrict__ log_A_real, const float* __restrict__ A_imag,
    float* __restrict__ Kbuf) {
    int h = blockIdx.x;
    int t = threadIdx.x;
    __shared__ float dre[N_], dim[N_], cre[N_], cim[N_];
    __shared__ float2 Thi[64 * 64];   // 32 KB
    __shared__ float2 Elo[64 * 32];   // 16 KB
    if (t < N_) {
        float dt = expf(log_dt[h]);
        float a_re = -expf(log_A_real[h * N_ + t]);
        float a_im = A_imag[h * N_ + t];
        float dA_re = a_re * dt, dA_im = a_im * dt;
        float er = expf(dA_re);
        float s, c;
        sincosf(dA_im, &s, &c);
        float num_re = er * c - 1.0f, num_im = er * s;
        float den = a_re * a_re + a_im * a_im;
        float q_re = (num_re * a_re + num_im * a_im) / den;
        float q_im = (num_im * a_re - num_re * a_im) / den;
        float Cr = C_ri[(h * N_ + t) * 2 + 0];
        float Ci = C_ri[(h * N_ + t) * 2 + 1];
        cre[t] = Cr * q_re - Ci * q_im;
        cim[t] = Cr * q_im + Ci * q_re;
        dre[t] = dA_re; dim[t] = dA_im;
    }
    __syncthreads();
    #pragma unroll
    for (int i = 0; i < 16; ++i) {
        int id = t + 256 * i;
        int n = id >> 6, q = id & 63;
        float a = (float)(32 * q);
        float er = expf(dre[n] * a);
        float s, c;
        sincosf(dim[n] * a, &s, &c);
        Thi[id] = make_float2(er * (cre[n] * c - cim[n] * s),
                              er * (cre[n] * s + cim[n] * c));
    }
    #pragma unroll
    for (int i = 0; i < 8; ++i) {
        int id = t + 256 * i;
        int n = id >> 5, r = id & 31;
        float a = (float)r;
        float er = expf(dre[n] * a);
        float s, c;
        sincosf(dim[n] * a, &s, &c);
        Elo[id] = make_float2(er * c, er * s);
    }
    __syncthreads();
    int q = t >> 2, r0 = (t & 3) * 8;
    float acc[8] = {};
    for (int n = 0; n < 64; ++n) {
        float2 T = Thi[n * 64 + q];
        const float2* e = &Elo[n * 32 + r0];
        #pragma unroll
        for (int j = 0; j < 8; ++j)
            acc[j] += T.x * e[j].x - T.y * e[j].y;
    }
    float* out = Kbuf + (size_t)h * L_ + t * 8;
    #pragma unroll
    for (int j = 0; j < 8; ++j) out[j] = 2.0f * acc[j];
}

// ---------------------------------------------------------------- FiLM
__global__ void k_film(const float* __restrict__ cond,
                       const float* __restrict__ film_w,
                       const float* __restrict__ film_b,
                       float* __restrict__ gb) {
    int j = blockIdx.x * 256 + threadIdx.x;
    int b  = j >> 10;
    int jj = j & 1023;
    float acc = film_b[jj];
    for (int c = 0; c < CD_; ++c)
        acc += cond[b * CD_ + c] * film_w[jj * CD_ + c];
    gb[j] = acc;
}

// ---------------------------------------------------------------- linear v4 (unchanged from r11)
__global__ __launch_bounds__(512, 4) void k_linear4(
    const float* __restrict__ x, const float* __restrict__ W,
    const float* __restrict__ bias, float* __restrict__ hbuf) {
    int b  = blockIdx.z;
    int g0 = blockIdx.y * 128;
    int l0 = blockIdx.x * 128;
    __shared__ __align__(16) u16 Wp[128 * 64];
    __shared__ __align__(16) u16 Bl[128 * 72];
    int t = threadIdx.x;
    int lane = t & 63, wv = t >> 6;
    int n = lane & 15, kg = lane >> 4;
    int wr = wv >> 2, wc = wv & 3;
    int lr  = t & 127, kq = t >> 7;
    int rw  = (t >> 4) & 31;
    int f16 = t & 15;

    f32x4 acc[4][2];
    #pragma unroll
    for (int m = 0; m < 4; ++m)
        #pragma unroll
        for (int q = 0; q < 2; ++q) acc[m][q] = (f32x4){0.f, 0.f, 0.f, 0.f};

    const float* xcol = x + (size_t)b * H_ * L_ + l0 + lr;
    float  cx[16], nx[16];
    float4 cw[4],  nw[4];
    #pragma unroll
    for (int e = 0; e < 16; ++e) cx[e] = xcol[(size_t)(kq * 16 + e) * L_];
    #pragma unroll
    for (int e = 0; e < 4; ++e)
        cw[e] = *(const float4*)&W[(size_t)(g0 + rw + 32 * e) * H_ + f16 * 4];

    #pragma unroll
    for (int S = 0; S < 8; ++S) {
        if (S) __syncthreads();
        {
            u32 px[8];
            #pragma unroll
            for (int e = 0; e < 8; ++e) px[e] = pack2(cx[2 * e], cx[2 * e + 1]);
            uint4 u0 = {px[0], px[1], px[2], px[3]};
            uint4 u1 = {px[4], px[5], px[6], px[7]};
            *(uint4*)((char*)Bl + lr * 144 + kq * 32)      = u0;
            *(uint4*)((char*)Bl + lr * 144 + kq * 32 + 16) = u1;
        }
        #pragma unroll
        for (int e = 0; e < 4; ++e) {
            int row = rw + 32 * e;
            uint2 pw;
            pw.x = pack2(cw[e].x, cw[e].y);
            pw.y = pack2(cw[e].z, cw[e].w);
            *(uint2*)((char*)Wp + row * 128 + ((f16 * 8) ^ ((row & 7) << 4))) = pw;
        }
        __syncthreads();
        if (S < 7) {
            int k0n = (S + 1) * 64;
            #pragma unroll
            for (int e = 0; e < 16; ++e) nx[e] = xcol[(size_t)(k0n + kq * 16 + e) * L_];
            #pragma unroll
            for (int e = 0; e < 4; ++e)
                nw[e] = *(const float4*)&W[(size_t)(g0 + rw + 32 * e) * H_ + k0n + f16 * 4];
        }
        #pragma unroll
        for (int ks = 0; ks < 2; ++ks) {
            bf16x8 af[4], bfr[2];
            #pragma unroll
            for (int m = 0; m < 4; ++m) {
                int row = wr * 64 + m * 16 + n;
                af[m] = *(const bf16x8*)((const char*)Wp + row * 128 +
                         ((ks * 64 + kg * 16) ^ ((n & 7) << 4)));
            }
            #pragma unroll
            for (int q = 0; q < 2; ++q)
                bfr[q] = *(const bf16x8*)((const char*)Bl +
                          (wc * 32 + q * 16 + n) * 144 + ks * 64 + kg * 16);
            #pragma unroll
            for (int m = 0; m < 4; ++m)
                #pragma unroll
                for (int q = 0; q < 2; ++q)
                    acc[m][q] = __builtin_amdgcn_mfma_f32_16x16x32_bf16(
                        af[m], bfr[q], acc[m][q], 0, 0, 0);
        }
        if (S < 7) {
            #pragma unroll
            for (int e = 0; e < 16; ++e) cx[e] = nx[e];
            #pragma unroll
            for (int e = 0; e < 4; ++e)  cw[e] = nw[e];
        }
    }

    #pragma unroll
    for (int m = 0; m < 4; ++m) {
        #pragma unroll
        for (int r = 0; r < 4; ++r) {
            int g = g0 + wr * 64 + m * 16 + kg * 4 + r;
            float bi = bias[g];
            float* dst = &hbuf[((size_t)b * H_ + g) * L_ + l0 + wc * 32 + n];
            #pragma unroll
            for (int q = 0; q < 2; ++q)
                dst[q * 16] = gelu_f(acc[m][q][r] + bi);
        }
    }
}

// ---------------------------------------------------------------- conv v2: sliding-window band MFMA
// One block per g. Wave wv (p=wv&1, q4=wv>>1) owns 4 runs rr in {q4,7-q4,8+q4,15-q4};
// run = 4 l-tiles l0 = 16p + 128rr + 32m. Band step c: dd = 16p+32c; per step:
// 1 new A-frag (H, b128 slide) + 1 B-frag (K window, 2x b64) + 4 MFMAs.
#define LDA(j0) (*(const bf16x8*)(smem + rowbase + (((u32)((j0) * 2 + kg16)) ^ swz)))
__global__ __launch_bounds__(512, 4) void k_conv_mfma(
    float* __restrict__ hy, const float* __restrict__ Kbuf,
    const float* __restrict__ Dp, const float* __restrict__ x,
    const float* __restrict__ gb, const float* __restrict__ res_w) {
    int g = blockIdx.x;
    __shared__ __align__(16) char smem[81920];   // Hs 64KB + KD2 16KB (red aliased)
    uint2* KD2 = (uint2*)(smem + 65536);         // KD2[i] = Krev[i..i+3] bf16
    int t = threadIdx.x;
    int wv = t >> 6, lane = t & 63;
    int n = lane & 15, kg = lane >> 4;

    // ---- stage KD2: Krev[i] = K[2047-i], 0 beyond
    const float* Kg = Kbuf + (size_t)g * L_;
    #pragma unroll
    for (int i0 = 0; i0 < 4; ++i0) {
        int i = t + 512 * i0;
        float f0 = Kg[L_ - 1 - i];
        float f1 = (i + 1 < L_) ? Kg[L_ - 2 - i] : 0.f;
        float f2 = (i + 2 < L_) ? Kg[L_ - 3 - i] : 0.f;
        float f3 = (i + 3 < L_) ? Kg[L_ - 4 - i] : 0.f;
        uint2 w; w.x = pack2(f0, f1); w.y = pack2(f2, f3);
        KD2[i] = w;
    }
    // ---- stage Hs: [16 b][2048] bf16, XOR-swizzled (byte ^= (b&7)<<4)
    for (int b = 0; b < B_; ++b) {
        float4 v = *(const float4*)&hy[((size_t)b * H_ + g) * L_ + t * 4];
        uint2 p2; p2.x = pack2(v.x, v.y); p2.y = pack2(v.z, v.w);
        *(uint2*)(smem + b * 4096 + (((u32)(t * 8)) ^ ((b & 7) << 4))) = p2;
    }
    __syncthreads();

    const int p = wv & 1, q4 = wv >> 1;
    const int rowbase = n * 4096;
    const u32 swz = (u32)((n & 7) << 4);
    const int kg16 = kg * 16;
    const int bofs = 8 * kg - n;      // K-window base offset per lane

    f32x4 acc[4][4];
    #pragma unroll
    for (int ri = 0; ri < 4; ++ri)
        #pragma unroll
        for (int m = 0; m < 4; ++m) acc[ri][m] = (f32x4){0.f, 0.f, 0.f, 0.f};

    const int rrs[4] = {q4, 7 - q4, 8 + q4, 15 - q4};
    #pragma unroll
    for (int ri = 0; ri < 4; ++ri) {
        const int k = 4 * rrs[ri];    // j0 = 32*(k + m - c)
        bf16x8 af0 = LDA(32 * (k + 0));
        bf16x8 af1 = LDA(32 * (k + 1));
        bf16x8 af2 = LDA(32 * (k + 2));
        bf16x8 af3 = LDA(32 * (k + 3));
        union { u32 u[4]; bf16x8 v; } bu;
        // ---- c = 0 (diagonal, masked K reads; base in [2016, 2071])
        {
            int base = 2047 - 16 * p + bofs;
            int b0 = base < 2047 ? base : 2047;
            int b1 = (base + 4) < 2047 ? (base + 4) : 2047;
            uint2 w01 = KD2[b0];
            uint2 w23 = KD2[b1];
            if (base > 2047)     { w01.x = 0u; w01.y = 0u; }
            if (base + 4 > 2047) { w23.x = 0u; w23.y = 0u; }
            bu.u[0] = w01.x; bu.u[1] = w01.y; bu.u[2] = w23.x; bu.u[3] = w23.y;
            acc[ri][0] = __builtin_amdgcn_mfma_f32_16x16x32_bf16(af0, bu.v, acc[ri][0], 0, 0, 0);
            acc[ri][1] = __builtin_amdgcn_mfma_f32_16x16x32_bf16(af1, bu.v, acc[ri][1], 0, 0, 0);
            acc[ri][2] = __builtin_amdgcn_mfma_f32_16x16x32_bf16(af2, bu.v, acc[ri][2], 0, 0, 0);
            acc[ri][3] = __builtin_amdgcn_mfma_f32_16x16x32_bf16(af3, bu.v, acc[ri][3], 0, 0, 0);
            af3 = af2; af2 = af1; af1 = af0;
            if (k >= 1) af0 = LDA(32 * (k - 1));
        }
        // ---- c = 1..k (interior: base in [0, 2043], no masking)
        for (int c = 1; c <= k; ++c) {
            int base = 2047 - 16 * p - 32 * c + bofs;
            uint2 w01 = KD2[base];
            uint2 w23 = KD2[base + 4];
            bu.u[0] = w01.x; bu.u[1] = w01.y; bu.u[2] = w23.x; bu.u[3] = w23.y;
            acc[ri][0] = __builtin_amdgcn_mfma_f32_16x16x32_bf16(af0, bu.v, acc[ri][0], 0, 0, 0);
            acc[ri][1] = __builtin_amdgcn_mfma_f32_16x16x32_bf16(af1, bu.v, acc[ri][1], 0, 0, 0);
            acc[ri][2] = __builtin_amdgcn_mfma_f32_16x16x32_bf16(af2, bu.v, acc[ri][2], 0, 0, 0);
            acc[ri][3] = __builtin_amdgcn_mfma_f32_16x16x32_bf16(af3, bu.v, acc[ri][3], 0, 0, 0);
            af3 = af2; af2 = af1; af1 = af0;
            int jn = k - c - 1;
            if (jn >= 0) af0 = LDA(32 * jn);
        }
        // ---- tails c = k+1, k+2, k+3 (3, 2, 1 active tiles)
        #pragma unroll
        for (int e = 1; e <= 3; ++e) {
            int base = 2047 - 16 * p - 32 * (k + e) + bofs;
            uint2 w01 = KD2[base];
            uint2 w23 = KD2[base + 4];
            bu.u[0] = w01.x; bu.u[1] = w01.y; bu.u[2] = w23.x; bu.u[3] = w23.y;
            if (e <= 1) acc[ri][1] = __builtin_amdgcn_mfma_f32_16x16x32_bf16(af1, bu.v, acc[ri][1], 0, 0, 0);
            if (e <= 2) acc[ri][2] = __builtin_amdgcn_mfma_f32_16x16x32_bf16(af2, bu.v, acc[ri][2], 0, 0, 0);
            acc[ri][3] = __builtin_amdgcn_mfma_f32_16x16x32_bf16(af3, bu.v, acc[ri][3], 0, 0, 0);
            af3 = af2; af2 = af1;
        }
    }

    // ---- epilogue: y = conv + D*h ; stats ; BN + FiLM + gelu + residual
    float Dg = Dp[g];
    float sum = 0.f, sq = 0.f;
    #pragma unroll
    for (int ri = 0; ri < 4; ++ri) {
        #pragma unroll
        for (int m = 0; m < 4; ++m) {
            const int l0 = 16 * p + 128 * rrs[ri] + 32 * m;
            #pragma unroll
            for (int r = 0; r < 4; ++r) {
                int b = kg * 4 + r;
                float hval = bf2f(*(const u16*)(smem + b * 4096 +
                              (((u32)(2 * (l0 + n))) ^ ((b & 7) << 4))));
                float y = acc[ri][m][r] + Dg * hval;
                acc[ri][m][r] = y;
                sum += y; sq += y * y;
            }
        }
    }
    #pragma unroll
    for (int off = 32; off > 0; off >>= 1) {
        sum += __shfl_down(sum, off);
        sq  += __shfl_down(sq, off);
    }
    __syncthreads();                       // all KD2 reads done -> alias reductions
    float* red = (float*)(smem + 65536);   // red_s[8], red_q[8], bc[2]
    if (lane == 0) { red[wv] = sum; red[8 + wv] = sq; }
    __syncthreads();
    if (t == 0) {
        float s = 0.f, q = 0.f;
        #pragma unroll
        for (int i = 0; i < 8; ++i) { s += red[i]; q += red[8 + i]; }
        const float inv = 1.0f / (float)(B_ * L_);
        float mean = s * inv;
        float var = q * inv - mean * mean;
        red[16] = mean; red[17] = rsqrtf(var + 1e-5f);
    }
    __syncthreads();
    const float mean = red[16], rstd = red[17];
    const float rw = res_w[g];
    #pragma unroll
    for (int r = 0; r < 4; ++r) {
        int b = kg * 4 + r;
        float gf = gb[b * (2 * H_) + g];
        float bb = gb[b * (2 * H_) + H_ + g];
        #pragma unroll
        for (int ri = 0; ri < 4; ++ri) {
            #pragma unroll
            for (int m = 0; m < 4; ++m) {
                const int l0 = 16 * p + 128 * rrs[ri] + 32 * m;
                size_t idx = ((size_t)b * H_ + g) * L_ + l0 + n;
                float yn = (acc[ri][m][r] - mean) * rstd;
                hy[idx] = gelu_f(yn * gf + bb) + x[idx] * rw;
            }
        }
    }
}

// ---------------------------------------------------------------- launch
extern "C" void kernel_launch(void* const* d_in, const int* in_sizes, int n_in,
                              void* d_out, int out_size, void* d_ws, size_t ws_size,
                              hipStream_t stream) {
    const int expect[12] = {16777216, 2048, 262144, 512, 512, 65536,
                            32768, 32768, 512, 131072, 1024, 512};
    bool ok = (n_in == 12);
    if (ok) for (int i = 0; i < 12; ++i) if (in_sizes[i] != expect[i]) ok = false;
    if (!ok) {
        k_fill<<<(out_size + 255) / 256, 256, 0, stream>>>((float*)d_out, out_size, 1000.0f);
        return;
    }
    if (ws_size < ((size_t)H_ * L_ * 4 + (size_t)B_ * 2 * H_ * 4 + 1024)) {
        k_fill<<<(out_size + 255) / 256, 256, 0, stream>>>((float*)d_out, out_size, 2000.0f);
        return;
    }

    const float* x          = (const float*)d_in[0];
    const float* cond       = (const float*)d_in[1];
    const float* linear_w   = (const float*)d_in[2];
    const float* linear_b   = (const float*)d_in[3];
    const float* log_dt     = (const float*)d_in[4];
    const float* C_ri       = (const float*)d_in[5];
    const float* log_A_real = (const float*)d_in[6];
    const float* A_imag     = (const float*)d_in[7];
    const float* Dp         = (const float*)d_in[8];
    const float* film_w     = (const float*)d_in[9];
    const float* film_b     = (const float*)d_in[10];
    const float* res_w      = (const float*)d_in[11];

    float* hy = (float*)d_out;   // h -> final output, f32, B*H*L

    char* w = (char*)d_ws;
    float* Kbuf  = (float*)w;  w += (size_t)H_ * L_ * 4;        // 4 MB
    float* gb    = (float*)w;  w += (size_t)B_ * 2 * H_ * 4;    // 64 KB

    k_K3<<<H_, 256, 0, stream>>>(log_dt, C_ri, log_A_real, A_imag, Kbuf);
    k_film<<<(B_ * 2 * H_) / 256, 256, 0, stream>>>(cond, film_w, film_b, gb);
    dim3 gmm(L_ / 128, H_ / 128, B_);
    k_linear4<<<gmm, 512, 0, stream>>>(x, linear_w, linear_b, hy);
    k_conv_mfma<<<H_, 512, 0, stream>>>(hy, Kbuf, Dp, x, gb, res_w);
}

// Round 13
// 137.934 us; speedup vs baseline: 17.8979x; 1.0747x over previous
//
#include <hip/hip_runtime.h>
#include <math.h>

#define B_ 16
#define H_ 512
#define L_ 2048
#define N_ 64
#define CD_ 128

typedef unsigned int u32;
typedef unsigned short u16;
typedef __attribute__((ext_vector_type(8))) short bf16x8;   // 8 bf16 in 4 VGPRs
typedef __attribute__((ext_vector_type(4))) float f32x4;    // mfma 16x16x32 C/D

__device__ __forceinline__ float gelu_f(float v) {
    return 0.5f * v * (1.0f + erff(v * 0.70710678118654752f));
}
__device__ __forceinline__ float bf2f(u16 b) {
    union { u32 u; float f; } c; c.u = ((u32)b) << 16; return c.f;
}
__device__ __forceinline__ u16 f2bf(float f) {
    union { float f; u32 u; } c; c.f = f;
    u32 u = c.u;
    return (u16)((u + 0x7FFFu + ((u >> 16) & 1u)) >> 16);
}
__device__ __forceinline__ u32 pack2(float a, float b) {
    return (u32)f2bf(a) | ((u32)f2bf(b) << 16);
}
__device__ __forceinline__ float2 cmul(float2 a, float2 b) {
    return make_float2(a.x * b.x - a.y * b.y, a.x * b.y + a.y * b.x);
}

// ---------------------------------------------------------------- sentinel fill
__global__ void k_fill(float* __restrict__ out, int n, float val) {
    int i = blockIdx.x * 256 + threadIdx.x;
    if (i < n) out[i] = val;
}

// ---------------------------------------------------------------- K via power tables
// K[h][l] = 2*Re( sum_n Cm_n * E1^l ), E1 = exp(dtA). l = 256qh+32ql+8rh+j.
__global__ __launch_bounds__(256) void k_K4(
    const float* __restrict__ log_dt, const float* __restrict__ C_ri,
    const float* __restrict__ log_A_real, const float* __restrict__ A_imag,
    float* __restrict__ Kbuf) {
    int h = blockIdx.x, t = threadIdx.x;
    __shared__ float2 P1[N_][8], P8[N_][4], P32[N_][8], P256[N_][8], Cs[N_];
    if (t < N_) {
        int n = t;
        float dt = expf(log_dt[h]);
        float a_re = -expf(log_A_real[h * N_ + n]);
        float a_im = A_imag[h * N_ + n];
        float dre = a_re * dt, dim = a_im * dt;
        float er = expf(dre);
        float s, c;
        sincosf(dim, &s, &c);
        float2 E1 = make_float2(er * c, er * s);
        float num_re = E1.x - 1.0f, num_im = E1.y;
        float den = a_re * a_re + a_im * a_im;
        float q_re = (num_re * a_re + num_im * a_im) / den;
        float q_im = (num_im * a_re - num_re * a_im) / den;
        float Cr = C_ri[(h * N_ + n) * 2 + 0], Ci = C_ri[(h * N_ + n) * 2 + 1];
        Cs[n] = make_float2(Cr * q_re - Ci * q_im, Cr * q_im + Ci * q_re);
        float2 w = make_float2(1.f, 0.f);
        #pragma unroll
        for (int i = 0; i < 8; ++i) { P1[n][i] = w; w = cmul(w, E1); }
        float2 E8 = w; w = make_float2(1.f, 0.f);
        #pragma unroll
        for (int i = 0; i < 4; ++i) { P8[n][i] = w; w = cmul(w, E8); }
        float2 E32 = w; w = make_float2(1.f, 0.f);
        #pragma unroll
        for (int i = 0; i < 8; ++i) { P32[n][i] = w; w = cmul(w, E32); }
        float2 E256 = w; w = make_float2(1.f, 0.f);
        #pragma unroll
        for (int i = 0; i < 8; ++i) { P256[n][i] = w; w = cmul(w, E256); }
    }
    __syncthreads();
    int qh = t >> 5, ql = (t >> 2) & 7, rh = t & 3;
    float acc[8] = {};
    for (int n = 0; n < N_; ++n) {
        float2 a = cmul(Cs[n], P256[n][qh]);
        a = cmul(a, P32[n][ql]);
        a = cmul(a, P8[n][rh]);
        #pragma unroll
        for (int j = 0; j < 8; ++j) {
            float2 e = P1[n][j];
            acc[j] += a.x * e.x - a.y * e.y;
        }
    }
    float* out = Kbuf + (size_t)h * L_ + t * 8;
    #pragma unroll
    for (int j = 0; j < 8; ++j) out[j] = 2.0f * acc[j];
}

// ---------------------------------------------------------------- linear v4 (+ optional bf16 h output)
__global__ __launch_bounds__(512, 4) void k_linear4(
    const float* __restrict__ x, const float* __restrict__ W,
    const float* __restrict__ bias, float* __restrict__ hf32,
    u16* __restrict__ hb16, int bf16h) {
    int b  = blockIdx.z;
    int g0 = blockIdx.y * 128;
    int l0 = blockIdx.x * 128;
    __shared__ __align__(16) u16 Wp[128 * 64];
    __shared__ __align__(16) u16 Bl[128 * 72];
    int t = threadIdx.x;
    int lane = t & 63, wv = t >> 6;
    int n = lane & 15, kg = lane >> 4;
    int wr = wv >> 2, wc = wv & 3;
    int lr  = t & 127, kq = t >> 7;
    int rw  = (t >> 4) & 31;
    int f16 = t & 15;

    f32x4 acc[4][2];
    #pragma unroll
    for (int m = 0; m < 4; ++m)
        #pragma unroll
        for (int q = 0; q < 2; ++q) acc[m][q] = (f32x4){0.f, 0.f, 0.f, 0.f};

    const float* xcol = x + (size_t)b * H_ * L_ + l0 + lr;
    float  cx[16], nx[16];
    float4 cw[4],  nw[4];
    #pragma unroll
    for (int e = 0; e < 16; ++e) cx[e] = xcol[(size_t)(kq * 16 + e) * L_];
    #pragma unroll
    for (int e = 0; e < 4; ++e)
        cw[e] = *(const float4*)&W[(size_t)(g0 + rw + 32 * e) * H_ + f16 * 4];

    #pragma unroll
    for (int S = 0; S < 8; ++S) {
        if (S) __syncthreads();
        {
            u32 px[8];
            #pragma unroll
            for (int e = 0; e < 8; ++e) px[e] = pack2(cx[2 * e], cx[2 * e + 1]);
            uint4 u0 = {px[0], px[1], px[2], px[3]};
            uint4 u1 = {px[4], px[5], px[6], px[7]};
            *(uint4*)((char*)Bl + lr * 144 + kq * 32)      = u0;
            *(uint4*)((char*)Bl + lr * 144 + kq * 32 + 16) = u1;
        }
        #pragma unroll
        for (int e = 0; e < 4; ++e) {
            int row = rw + 32 * e;
            uint2 pw;
            pw.x = pack2(cw[e].x, cw[e].y);
            pw.y = pack2(cw[e].z, cw[e].w);
            *(uint2*)((char*)Wp + row * 128 + ((f16 * 8) ^ ((row & 7) << 4))) = pw;
        }
        __syncthreads();
        if (S < 7) {
            int k0n = (S + 1) * 64;
            #pragma unroll
            for (int e = 0; e < 16; ++e) nx[e] = xcol[(size_t)(k0n + kq * 16 + e) * L_];
            #pragma unroll
            for (int e = 0; e < 4; ++e)
                nw[e] = *(const float4*)&W[(size_t)(g0 + rw + 32 * e) * H_ + k0n + f16 * 4];
        }
        #pragma unroll
        for (int ks = 0; ks < 2; ++ks) {
            bf16x8 af[4], bfr[2];
            #pragma unroll
            for (int m = 0; m < 4; ++m) {
                int row = wr * 64 + m * 16 + n;
                af[m] = *(const bf16x8*)((const char*)Wp + row * 128 +
                         ((ks * 64 + kg * 16) ^ ((n & 7) << 4)));
            }
            #pragma unroll
            for (int q = 0; q < 2; ++q)
                bfr[q] = *(const bf16x8*)((const char*)Bl +
                          (wc * 32 + q * 16 + n) * 144 + ks * 64 + kg * 16);
            #pragma unroll
            for (int m = 0; m < 4; ++m)
                #pragma unroll
                for (int q = 0; q < 2; ++q)
                    acc[m][q] = __builtin_amdgcn_mfma_f32_16x16x32_bf16(
                        af[m], bfr[q], acc[m][q], 0, 0, 0);
        }
        if (S < 7) {
            #pragma unroll
            for (int e = 0; e < 16; ++e) cx[e] = nx[e];
            #pragma unroll
            for (int e = 0; e < 4; ++e)  cw[e] = nw[e];
        }
    }

    #pragma unroll
    for (int m = 0; m < 4; ++m) {
        #pragma unroll
        for (int r = 0; r < 4; ++r) {
            int g = g0 + wr * 64 + m * 16 + kg * 4 + r;
            float bi = bias[g];
            float v0 = gelu_f(acc[m][0][r] + bi);
            float v1 = gelu_f(acc[m][1][r] + bi);
            size_t off = ((size_t)b * H_ + g) * L_ + l0 + wc * 32 + n;
            if (bf16h) {
                hb16[off]      = f2bf(v0);
                hb16[off + 16] = f2bf(v1);
            } else {
                hf32[off]      = v0;
                hf32[off + 16] = v1;
            }
        }
    }
}

// ---------------------------------------------------------------- conv band step (templated, statically renamed ring)
template<int E, bool DIAG, bool TAIL, bool LOAD>
__device__ __forceinline__ void cstep(const uint2* __restrict__ KD2, int& base,
    bf16x8 (&ring)[8], f32x4 (&accR)[8], const char* smem,
    int rowbase, u32 swz, int kg16, int& ja) {
    uint2 w01, w23;
    if (DIAG) {
        int b0 = base < 2047 ? base : 2047;
        int b1 = (base + 4) < 2047 ? (base + 4) : 2047;
        w01 = KD2[b0];
        w23 = KD2[b1];
        if (base > 2047)     { w01.x = 0u; w01.y = 0u; }
        if (base + 4 > 2047) { w23.x = 0u; w23.y = 0u; }
    } else {
        w01 = KD2[base];
        w23 = KD2[base + 4];
    }
    union { u32 u[4]; bf16x8 v; } bu;
    bu.u[0] = w01.x; bu.u[1] = w01.y; bu.u[2] = w23.x; bu.u[3] = w23.y;
    #pragma unroll
    for (int m = 0; m < 8; ++m)
        if (!TAIL || m >= E)
            accR[m] = __builtin_amdgcn_mfma_f32_16x16x32_bf16(
                ring[(m - E) & 7], bu.v, accR[m], 0, 0, 0);
    if (LOAD) {
        ring[(7 - E) & 7] = *(const bf16x8*)(smem + rowbase +
                            (((u32)(ja * 64 + kg16)) ^ swz));
        ja -= 1;
    }
    base -= 32;
}

template<bool DIAG, bool TAIL, bool LOAD>
__device__ __forceinline__ void cblock8(const uint2* __restrict__ KD2, int& base,
    bf16x8 (&ring)[8], f32x4 (&accR)[8], const char* smem,
    int rowbase, u32 swz, int kg16, int& ja) {
    cstep<0, DIAG,  TAIL, LOAD>(KD2, base, ring, accR, smem, rowbase, swz, kg16, ja);
    cstep<1, false, TAIL, LOAD>(KD2, base, ring, accR, smem, rowbase, swz, kg16, ja);
    cstep<2, false, TAIL, LOAD>(KD2, base, ring, accR, smem, rowbase, swz, kg16, ja);
    cstep<3, false, TAIL, LOAD>(KD2, base, ring, accR, smem, rowbase, swz, kg16, ja);
    cstep<4, false, TAIL, LOAD>(KD2, base, ring, accR, smem, rowbase, swz, kg16, ja);
    cstep<5, false, TAIL, LOAD>(KD2, base, ring, accR, smem, rowbase, swz, kg16, ja);
    cstep<6, false, TAIL, LOAD>(KD2, base, ring, accR, smem, rowbase, swz, kg16, ja);
    cstep<7, false, TAIL, LOAD>(KD2, base, ring, accR, smem, rowbase, swz, kg16, ja);
}

// ---------------------------------------------------------------- conv v3: runs-of-8 band MFMA + film + BN + gelu + residual
__global__ __launch_bounds__(512, 4) void k_conv_mfma(
    float* __restrict__ out, const u16* __restrict__ hb16,
    const float* __restrict__ hf32, int bf16h,
    const float* __restrict__ Kbuf, const float* __restrict__ Dp,
    const float* __restrict__ x, const float* __restrict__ cond,
    const float* __restrict__ film_w, const float* __restrict__ film_b,
    const float* __restrict__ res_w) {
    int g = blockIdx.x;
    __shared__ __align__(16) char smem[81920];   // Hs 64KB + KD2 16KB (red/film aliased)
    uint2* KD2 = (uint2*)(smem + 65536);
    int t = threadIdx.x;
    int wv = t >> 6, lane = t & 63;
    int n = lane & 15, kg = lane >> 4;

    // ---- stage KD2: Krev[i] = K[2047-i]
    const float* Kg = Kbuf + (size_t)g * L_;
    #pragma unroll
    for (int i0 = 0; i0 < 4; ++i0) {
        int i = t + 512 * i0;
        float f0 = Kg[L_ - 1 - i];
        float f1 = (i + 1 < L_) ? Kg[L_ - 2 - i] : 0.f;
        float f2 = (i + 2 < L_) ? Kg[L_ - 3 - i] : 0.f;
        float f3 = (i + 3 < L_) ? Kg[L_ - 4 - i] : 0.f;
        uint2 w; w.x = pack2(f0, f1); w.y = pack2(f2, f3);
        KD2[i] = w;
    }
    // ---- stage Hs: [16 b][2048] bf16, XOR-swizzled
    if (bf16h) {
        #pragma unroll
        for (int b = 0; b < B_; ++b) {
            uint2 p2 = *(const uint2*)&hb16[((size_t)b * H_ + g) * L_ + t * 4];
            *(uint2*)(smem + b * 4096 + (((u32)(t * 8)) ^ ((b & 7) << 4))) = p2;
        }
    } else {
        #pragma unroll
        for (int b = 0; b < B_; ++b) {
            float4 v = *(const float4*)&hf32[((size_t)b * H_ + g) * L_ + t * 4];
            uint2 p2; p2.x = pack2(v.x, v.y); p2.y = pack2(v.z, v.w);
            *(uint2*)(smem + b * 4096 + (((u32)(t * 8)) ^ ((b & 7) << 4))) = p2;
        }
    }
    __syncthreads();

    const int p = wv & 1, q4 = wv >> 1;
    const int rowbase = n * 4096;
    const u32 swz = (u32)((n & 7) << 4);
    const int kg16 = kg * 16;
    const int bofs = 8 * kg - n;
    const int rrs[2] = {q4, 7 - q4};

    f32x4 acc[2][8];
    #pragma unroll
    for (int ri = 0; ri < 2; ++ri)
        #pragma unroll
        for (int m = 0; m < 8; ++m) acc[ri][m] = (f32x4){0.f, 0.f, 0.f, 0.f};

    #pragma unroll
    for (int ri = 0; ri < 2; ++ri) {
        const int rr = rrs[ri];
        const int k8 = rr * 8;            // l0(m) = 16p + 256rr + 32m; j0 = 32(k8+m-c)
        bf16x8 ring[8];
        #pragma unroll
        for (int m = 0; m < 8; ++m)
            ring[m] = *(const bf16x8*)(smem + rowbase +
                      (((u32)((k8 + m) * 64 + kg16)) ^ swz));
        int base = 2047 - 16 * p + bofs;
        int ja = k8 - 1;
        if (rr == 0) {
            cblock8<true, true, false>(KD2, base, ring, acc[ri], smem, rowbase, swz, kg16, ja);
        } else {
            cblock8<true, false, true>(KD2, base, ring, acc[ri], smem, rowbase, swz, kg16, ja);
            for (int bi = 1; bi < rr; ++bi)
                cblock8<false, false, true>(KD2, base, ring, acc[ri], smem, rowbase, swz, kg16, ja);
            cblock8<false, true, false>(KD2, base, ring, acc[ri], smem, rowbase, swz, kg16, ja);
        }
    }

    // ---- epilogue 1: y = conv + D*h ; per-thread stats
    float Dg = Dp[g];
    float sum = 0.f, sq = 0.f;
    #pragma unroll
    for (int ri = 0; ri < 2; ++ri) {
        #pragma unroll
        for (int m = 0; m < 8; ++m) {
            const int l0 = 16 * p + 256 * rrs[ri] + 32 * m;
            #pragma unroll
            for (int r = 0; r < 4; ++r) {
                int b = kg * 4 + r;
                float hval = bf2f(*(const u16*)(smem + b * 4096 +
                              (((u32)(2 * (l0 + n))) ^ ((b & 7) << 4))));
                float y = acc[ri][m][r] + Dg * hval;
                acc[ri][m][r] = y;
                sum += y; sq += y * y;
            }
        }
    }
    #pragma unroll
    for (int off = 32; off > 0; off >>= 1) {
        sum += __shfl_down(sum, off);
        sq  += __shfl_down(sq, off);
    }
    __syncthreads();                       // KD2 reads done -> alias scratch
    float* red = (float*)(smem + 65536);   // [0..7] s, [8..15] q, 16 mean, 17 rstd, [18..49] film
    if (lane == 0) { red[wv] = sum; red[8 + wv] = sq; }
    // ---- film: 32 dot-products cond[b,:]·film_w[row,:]
    if (t >= 64 && t < 96) {
        int tid = t - 64, b = tid >> 1, which = tid & 1;
        int row = which ? (H_ + g) : g;
        float a = film_b[row];
        const float4* wr4 = (const float4*)(film_w + (size_t)row * CD_);
        const float4* cp4 = (const float4*)(cond + b * CD_);
        #pragma unroll
        for (int c4 = 0; c4 < CD_ / 4; ++c4) {
            float4 cw = cp4[c4], ww = wr4[c4];
            a += cw.x * ww.x + cw.y * ww.y + cw.z * ww.z + cw.w * ww.w;
        }
        red[18 + tid] = a;
    }
    __syncthreads();
    if (t == 0) {
        float s = 0.f, q = 0.f;
        #pragma unroll
        for (int i = 0; i < 8; ++i) { s += red[i]; q += red[8 + i]; }
        const float inv = 1.0f / (float)(B_ * L_);
        float mean = s * inv;
        float var = q * inv - mean * mean;
        red[16] = mean; red[17] = rsqrtf(var + 1e-5f);
    }
    __syncthreads();
    const float mean = red[16], rstd = red[17];
    const float rw = res_w[g];
    #pragma unroll
    for (int r = 0; r < 4; ++r) {
        int b = kg * 4 + r;
        float gf = red[18 + 2 * b];
        float bb = red[18 + 2 * b + 1];
        #pragma unroll
        for (int ri = 0; ri < 2; ++ri) {
            #pragma unroll
            for (int m = 0; m < 8; ++m) {
                const int l0 = 16 * p + 256 * rrs[ri] + 32 * m;
                size_t idx = ((size_t)b * H_ + g) * L_ + l0 + n;
                float yn = (acc[ri][m][r] - mean) * rstd;
                out[idx] = gelu_f(yn * gf + bb) + x[idx] * rw;
            }
        }
    }
}

// ---------------------------------------------------------------- launch
extern "C" void kernel_launch(void* const* d_in, const int* in_sizes, int n_in,
                              void* d_out, int out_size, void* d_ws, size_t ws_size,
                              hipStream_t stream) {
    const int expect[12] = {16777216, 2048, 262144, 512, 512, 65536,
                            32768, 32768, 512, 131072, 1024, 512};
    bool ok = (n_in == 12);
    if (ok) for (int i = 0; i < 12; ++i) if (in_sizes[i] != expect[i]) ok = false;
    if (!ok) {
        k_fill<<<(out_size + 255) / 256, 256, 0, stream>>>((float*)d_out, out_size, 1000.0f);
        return;
    }
    if (ws_size < (size_t)H_ * L_ * 4 + 4096) {
        k_fill<<<(out_size + 255) / 256, 256, 0, stream>>>((float*)d_out, out_size, 2000.0f);
        return;
    }

    const float* x          = (const float*)d_in[0];
    const float* cond       = (const float*)d_in[1];
    const float* linear_w   = (const float*)d_in[2];
    const float* linear_b   = (const float*)d_in[3];
    const float* log_dt     = (const float*)d_in[4];
    const float* C_ri       = (const float*)d_in[5];
    const float* log_A_real = (const float*)d_in[6];
    const float* A_imag     = (const float*)d_in[7];
    const float* Dp         = (const float*)d_in[8];
    const float* film_w     = (const float*)d_in[9];
    const float* film_b     = (const float*)d_in[10];
    const float* res_w      = (const float*)d_in[11];

    float* hy = (float*)d_out;   // f32-h fallback + final output

    char* w = (char*)d_ws;
    float* Kbuf = (float*)w;  w += (size_t)H_ * L_ * 4;          // 4 MB
    u16*   hb16 = (u16*)w;                                       // 33.5 MB (optional)
    const size_t need_bf16 = (size_t)H_ * L_ * 4 + (size_t)B_ * H_ * L_ * 2 + 4096;
    int bf16h = (ws_size >= need_bf16) ? 1 : 0;

    k_K4<<<H_, 256, 0, stream>>>(log_dt, C_ri, log_A_real, A_imag, Kbuf);
    dim3 gmm(L_ / 128, H_ / 128, B_);
    k_linear4<<<gmm, 512, 0, stream>>>(x, linear_w, linear_b, hy, hb16, bf16h);
    k_conv_mfma<<<H_, 512, 0, stream>>>(hy, hb16, hy, bf16h, Kbuf, Dp, x,
                                        cond, film_w, film_b, res_w);
}

// Round 14
// 121.517 us; speedup vs baseline: 20.3159x; 1.1351x over previous
//
#include <hip/hip_runtime.h>
#include <math.h>

#define B_ 16
#define H_ 512
#define L_ 2048
#define N_ 64
#define CD_ 128

typedef unsigned int u32;
typedef unsigned short u16;
typedef __attribute__((ext_vector_type(8))) short bf16x8;   // 8 bf16 in 4 VGPRs
typedef __attribute__((ext_vector_type(4))) float f32x4;    // mfma 16x16x32 C/D

__device__ __forceinline__ float gelu_f(float v) {
    return 0.5f * v * (1.0f + erff(v * 0.70710678118654752f));
}
__device__ __forceinline__ float bf2f(u16 b) {
    union { u32 u; float f; } c; c.u = ((u32)b) << 16; return c.f;
}
__device__ __forceinline__ u16 f2bf(float f) {
    union { float f; u32 u; } c; c.f = f;
    u32 u = c.u;
    return (u16)((u + 0x7FFFu + ((u >> 16) & 1u)) >> 16);
}
__device__ __forceinline__ u32 pack2(float a, float b) {
    return (u32)f2bf(a) | ((u32)f2bf(b) << 16);
}
__device__ __forceinline__ float2 cmul(float2 a, float2 b) {
    return make_float2(a.x * b.x - a.y * b.y, a.x * b.y + a.y * b.x);
}

// ---------------------------------------------------------------- sentinel fill
__global__ void k_fill(float* __restrict__ out, int n, float val) {
    int i = blockIdx.x * 256 + threadIdx.x;
    if (i < n) out[i] = val;
}

// ---------------------------------------------------------------- K via power tables
__global__ __launch_bounds__(256) void k_K4(
    const float* __restrict__ log_dt, const float* __restrict__ C_ri,
    const float* __restrict__ log_A_real, const float* __restrict__ A_imag,
    float* __restrict__ Kbuf) {
    int h = blockIdx.x, t = threadIdx.x;
    __shared__ float2 P1[N_][8], P8[N_][4], P32[N_][8], P256[N_][8], Cs[N_];
    if (t < N_) {
        int n = t;
        float dt = expf(log_dt[h]);
        float a_re = -expf(log_A_real[h * N_ + n]);
        float a_im = A_imag[h * N_ + n];
        float dre = a_re * dt, dim = a_im * dt;
        float er = expf(dre);
        float s, c;
        sincosf(dim, &s, &c);
        float2 E1 = make_float2(er * c, er * s);
        float num_re = E1.x - 1.0f, num_im = E1.y;
        float den = a_re * a_re + a_im * a_im;
        float q_re = (num_re * a_re + num_im * a_im) / den;
        float q_im = (num_im * a_re - num_re * a_im) / den;
        float Cr = C_ri[(h * N_ + n) * 2 + 0], Ci = C_ri[(h * N_ + n) * 2 + 1];
        Cs[n] = make_float2(Cr * q_re - Ci * q_im, Cr * q_im + Ci * q_re);
        float2 w = make_float2(1.f, 0.f);
        #pragma unroll
        for (int i = 0; i < 8; ++i) { P1[n][i] = w; w = cmul(w, E1); }
        float2 E8 = w; w = make_float2(1.f, 0.f);
        #pragma unroll
        for (int i = 0; i < 4; ++i) { P8[n][i] = w; w = cmul(w, E8); }
        float2 E32 = w; w = make_float2(1.f, 0.f);
        #pragma unroll
        for (int i = 0; i < 8; ++i) { P32[n][i] = w; w = cmul(w, E32); }
        float2 E256 = w; w = make_float2(1.f, 0.f);
        #pragma unroll
        for (int i = 0; i < 8; ++i) { P256[n][i] = w; w = cmul(w, E256); }
    }
    __syncthreads();
    int qh = t >> 5, ql = (t >> 2) & 7, rh = t & 3;
    float acc[8] = {};
    for (int n = 0; n < N_; ++n) {
        float2 a = cmul(Cs[n], P256[n][qh]);
        a = cmul(a, P32[n][ql]);
        a = cmul(a, P8[n][rh]);
        #pragma unroll
        for (int j = 0; j < 8; ++j) {
            float2 e = P1[n][j];
            acc[j] += a.x * e.x - a.y * e.y;
        }
    }
    float* out = Kbuf + (size_t)h * L_ + t * 8;
    #pragma unroll
    for (int j = 0; j < 8; ++j) out[j] = 2.0f * acc[j];
}

// ---------------------------------------------------------------- linear v4 (+ optional bf16 h output)
__global__ __launch_bounds__(512, 4) void k_linear4(
    const float* __restrict__ x, const float* __restrict__ W,
    const float* __restrict__ bias, float* __restrict__ hf32,
    u16* __restrict__ hb16, int bf16h) {
    int b  = blockIdx.z;
    int g0 = blockIdx.y * 128;
    int l0 = blockIdx.x * 128;
    __shared__ __align__(16) u16 Wp[128 * 64];
    __shared__ __align__(16) u16 Bl[128 * 72];
    int t = threadIdx.x;
    int lane = t & 63, wv = t >> 6;
    int n = lane & 15, kg = lane >> 4;
    int wr = wv >> 2, wc = wv & 3;
    int lr  = t & 127, kq = t >> 7;
    int rw  = (t >> 4) & 31;
    int f16 = t & 15;

    f32x4 acc[4][2];
    #pragma unroll
    for (int m = 0; m < 4; ++m)
        #pragma unroll
        for (int q = 0; q < 2; ++q) acc[m][q] = (f32x4){0.f, 0.f, 0.f, 0.f};

    const float* xcol = x + (size_t)b * H_ * L_ + l0 + lr;
    float  cx[16], nx[16];
    float4 cw[4],  nw[4];
    #pragma unroll
    for (int e = 0; e < 16; ++e) cx[e] = xcol[(size_t)(kq * 16 + e) * L_];
    #pragma unroll
    for (int e = 0; e < 4; ++e)
        cw[e] = *(const float4*)&W[(size_t)(g0 + rw + 32 * e) * H_ + f16 * 4];

    #pragma unroll
    for (int S = 0; S < 8; ++S) {
        if (S) __syncthreads();
        {
            u32 px[8];
            #pragma unroll
            for (int e = 0; e < 8; ++e) px[e] = pack2(cx[2 * e], cx[2 * e + 1]);
            uint4 u0 = {px[0], px[1], px[2], px[3]};
            uint4 u1 = {px[4], px[5], px[6], px[7]};
            *(uint4*)((char*)Bl + lr * 144 + kq * 32)      = u0;
            *(uint4*)((char*)Bl + lr * 144 + kq * 32 + 16) = u1;
        }
        #pragma unroll
        for (int e = 0; e < 4; ++e) {
            int row = rw + 32 * e;
            uint2 pw;
            pw.x = pack2(cw[e].x, cw[e].y);
            pw.y = pack2(cw[e].z, cw[e].w);
            *(uint2*)((char*)Wp + row * 128 + ((f16 * 8) ^ ((row & 7) << 4))) = pw;
        }
        __syncthreads();
        if (S < 7) {
            int k0n = (S + 1) * 64;
            #pragma unroll
            for (int e = 0; e < 16; ++e) nx[e] = xcol[(size_t)(k0n + kq * 16 + e) * L_];
            #pragma unroll
            for (int e = 0; e < 4; ++e)
                nw[e] = *(const float4*)&W[(size_t)(g0 + rw + 32 * e) * H_ + k0n + f16 * 4];
        }
        #pragma unroll
        for (int ks = 0; ks < 2; ++ks) {
            bf16x8 af[4], bfr[2];
            #pragma unroll
            for (int m = 0; m < 4; ++m) {
                int row = wr * 64 + m * 16 + n;
                af[m] = *(const bf16x8*)((const char*)Wp + row * 128 +
                         ((ks * 64 + kg * 16) ^ ((n & 7) << 4)));
            }
            #pragma unroll
            for (int q = 0; q < 2; ++q)
                bfr[q] = *(const bf16x8*)((const char*)Bl +
                          (wc * 32 + q * 16 + n) * 144 + ks * 64 + kg * 16);
            #pragma unroll
            for (int m = 0; m < 4; ++m)
                #pragma unroll
                for (int q = 0; q < 2; ++q)
                    acc[m][q] = __builtin_amdgcn_mfma_f32_16x16x32_bf16(
                        af[m], bfr[q], acc[m][q], 0, 0, 0);
        }
        if (S < 7) {
            #pragma unroll
            for (int e = 0; e < 16; ++e) cx[e] = nx[e];
            #pragma unroll
            for (int e = 0; e < 4; ++e)  cw[e] = nw[e];
        }
    }

    #pragma unroll
    for (int m = 0; m < 4; ++m) {
        #pragma unroll
        for (int r = 0; r < 4; ++r) {
            int g = g0 + wr * 64 + m * 16 + kg * 4 + r;
            float bi = bias[g];
            float v0 = gelu_f(acc[m][0][r] + bi);
            float v1 = gelu_f(acc[m][1][r] + bi);
            size_t off = ((size_t)b * H_ + g) * L_ + l0 + wc * 32 + n;
            if (bf16h) {
                hb16[off]      = f2bf(v0);
                hb16[off + 16] = f2bf(v1);
            } else {
                hf32[off]      = v0;
                hf32[off + 16] = v1;
            }
        }
    }
}

// ---------------------------------------------------------------- conv band step (templated, statically renamed ring)
template<int E, bool DIAG, bool TAIL, bool LOAD>
__device__ __forceinline__ void cstep(const uint2* __restrict__ KD2, int& base,
    bf16x8 (&ring)[8], f32x4 (&accR)[8], const char* smem,
    int rowbase, u32 swz, int kg16, int& ja) {
    uint2 w01, w23;
    if (DIAG) {
        int b0 = base < 2047 ? base : 2047;
        int b1 = (base + 4) < 2047 ? (base + 4) : 2047;
        w01 = KD2[b0];
        w23 = KD2[b1];
        if (base > 2047)     { w01.x = 0u; w01.y = 0u; }
        if (base + 4 > 2047) { w23.x = 0u; w23.y = 0u; }
    } else {
        w01 = KD2[base];
        w23 = KD2[base + 4];
    }
    union { u32 u[4]; bf16x8 v; } bu;
    bu.u[0] = w01.x; bu.u[1] = w01.y; bu.u[2] = w23.x; bu.u[3] = w23.y;
    #pragma unroll
    for (int m = 0; m < 8; ++m)
        if (!TAIL || m >= E)
            accR[m] = __builtin_amdgcn_mfma_f32_16x16x32_bf16(
                ring[(m - E) & 7], bu.v, accR[m], 0, 0, 0);
    if (LOAD) {
        ring[(7 - E) & 7] = *(const bf16x8*)(smem + rowbase +
                            (((u32)(ja * 64 + kg16)) ^ swz));
        ja -= 1;
    }
    base -= 32;
}

template<bool DIAG, bool TAIL, bool LOAD>
__device__ __forceinline__ void cblock8(const uint2* __restrict__ KD2, int& base,
    bf16x8 (&ring)[8], f32x4 (&accR)[8], const char* smem,
    int rowbase, u32 swz, int kg16, int& ja) {
    cstep<0, DIAG,  TAIL, LOAD>(KD2, base, ring, accR, smem, rowbase, swz, kg16, ja);
    cstep<1, false, TAIL, LOAD>(KD2, base, ring, accR, smem, rowbase, swz, kg16, ja);
    cstep<2, false, TAIL, LOAD>(KD2, base, ring, accR, smem, rowbase, swz, kg16, ja);
    cstep<3, false, TAIL, LOAD>(KD2, base, ring, accR, smem, rowbase, swz, kg16, ja);
    cstep<4, false, TAIL, LOAD>(KD2, base, ring, accR, smem, rowbase, swz, kg16, ja);
    cstep<5, false, TAIL, LOAD>(KD2, base, ring, accR, smem, rowbase, swz, kg16, ja);
    cstep<6, false, TAIL, LOAD>(KD2, base, ring, accR, smem, rowbase, swz, kg16, ja);
    cstep<7, false, TAIL, LOAD>(KD2, base, ring, accR, smem, rowbase, swz, kg16, ja);
}

// ---------------------------------------------------------------- conv v4: band MFMA + LDS-bounce coalesced epilogue
__global__ __launch_bounds__(512, 4) void k_conv_mfma(
    float* __restrict__ out, const u16* __restrict__ hb16,
    const float* __restrict__ hf32, int bf16h,
    const float* __restrict__ Kbuf, const float* __restrict__ Dp,
    const float* __restrict__ x, const float* __restrict__ cond,
    const float* __restrict__ film_w, const float* __restrict__ film_b,
    const float* __restrict__ res_w) {
    int g = blockIdx.x;
    __shared__ __align__(16) char smem[81920];   // Hs 64KB + KD2 16KB (red/film aliased)
    uint2* KD2 = (uint2*)(smem + 65536);
    int t = threadIdx.x;
    int wv = t >> 6, lane = t & 63;
    int n = lane & 15, kg = lane >> 4;

    // ---- stage KD2: Krev[i] = K[2047-i]
    const float* Kg = Kbuf + (size_t)g * L_;
    #pragma unroll
    for (int i0 = 0; i0 < 4; ++i0) {
        int i = t + 512 * i0;
        float f0 = Kg[L_ - 1 - i];
        float f1 = (i + 1 < L_) ? Kg[L_ - 2 - i] : 0.f;
        float f2 = (i + 2 < L_) ? Kg[L_ - 3 - i] : 0.f;
        float f3 = (i + 3 < L_) ? Kg[L_ - 4 - i] : 0.f;
        uint2 w; w.x = pack2(f0, f1); w.y = pack2(f2, f3);
        KD2[i] = w;
    }
    // ---- stage Hs: [16 b][2048] bf16, XOR-swizzled
    if (bf16h) {
        #pragma unroll
        for (int b = 0; b < B_; ++b) {
            uint2 p2 = *(const uint2*)&hb16[((size_t)b * H_ + g) * L_ + t * 4];
            *(uint2*)(smem + b * 4096 + (((u32)(t * 8)) ^ ((b & 7) << 4))) = p2;
        }
    } else {
        #pragma unroll
        for (int b = 0; b < B_; ++b) {
            float4 v = *(const float4*)&hf32[((size_t)b * H_ + g) * L_ + t * 4];
            uint2 p2; p2.x = pack2(v.x, v.y); p2.y = pack2(v.z, v.w);
            *(uint2*)(smem + b * 4096 + (((u32)(t * 8)) ^ ((b & 7) << 4))) = p2;
        }
    }
    __syncthreads();

    const int p = wv & 1, q4 = wv >> 1;
    const int rowbase = n * 4096;
    const u32 swz = (u32)((n & 7) << 4);
    const int kg16 = kg * 16;
    const int bofs = 8 * kg - n;
    const int rrs[2] = {q4, 7 - q4};

    f32x4 acc[2][8];
    #pragma unroll
    for (int ri = 0; ri < 2; ++ri)
        #pragma unroll
        for (int m = 0; m < 8; ++m) acc[ri][m] = (f32x4){0.f, 0.f, 0.f, 0.f};

    #pragma unroll
    for (int ri = 0; ri < 2; ++ri) {
        const int rr = rrs[ri];
        const int k8 = rr * 8;            // l0(m) = 16p + 256rr + 32m; j0 = 32(k8+m-c)
        bf16x8 ring[8];
        #pragma unroll
        for (int m = 0; m < 8; ++m)
            ring[m] = *(const bf16x8*)(smem + rowbase +
                      (((u32)((k8 + m) * 64 + kg16)) ^ swz));
        int base = 2047 - 16 * p + bofs;
        int ja = k8 - 1;
        if (rr == 0) {
            cblock8<true, true, false>(KD2, base, ring, acc[ri], smem, rowbase, swz, kg16, ja);
        } else {
            cblock8<true, false, true>(KD2, base, ring, acc[ri], smem, rowbase, swz, kg16, ja);
            for (int bi = 1; bi < rr; ++bi)
                cblock8<false, false, true>(KD2, base, ring, acc[ri], smem, rowbase, swz, kg16, ja);
            cblock8<false, true, false>(KD2, base, ring, acc[ri], smem, rowbase, swz, kg16, ja);
        }
    }

    // ---- phase 2: y = conv + D*h ; stats ; y (bf16) back into Hs slots
    __syncthreads();                      // all waves done with A-frag/KD2 reads
    float Dg = Dp[g];
    float sum = 0.f, sq = 0.f;
    #pragma unroll
    for (int ri = 0; ri < 2; ++ri) {
        #pragma unroll
        for (int m = 0; m < 8; ++m) {
            const int l0 = 16 * p + 256 * rrs[ri] + 32 * m;
            #pragma unroll
            for (int r = 0; r < 4; ++r) {
                int b = kg * 4 + r;
                u32 hoff = ((u32)(2 * (l0 + n))) ^ ((u32)((b & 7) << 4));
                float hval = bf2f(*(const u16*)(smem + b * 4096 + hoff));
                float y = acc[ri][m][r] + Dg * hval;
                sum += y; sq += y * y;
                *(u16*)(smem + b * 4096 + hoff) = f2bf(y);   // own slot (bijective)
            }
        }
    }
    #pragma unroll
    for (int off = 32; off > 0; off >>= 1) {
        sum += __shfl_down(sum, off);
        sq  += __shfl_down(sq, off);
    }
    __syncthreads();                       // y writes done; KD2 free -> alias scratch
    float* red = (float*)(smem + 65536);   // [0..7] s, [8..15] q, 16 mean, 17 rstd, [18..49] film
    if (lane == 0) { red[wv] = sum; red[8 + wv] = sq; }
    if (t >= 64 && t < 96) {               // film: 32 dot-products
        int tid = t - 64, b = tid >> 1, which = tid & 1;
        int row = which ? (H_ + g) : g;
        float a = film_b[row];
        const float4* wr4 = (const float4*)(film_w + (size_t)row * CD_);
        const float4* cp4 = (const float4*)(cond + b * CD_);
        #pragma unroll
        for (int c4 = 0; c4 < CD_ / 4; ++c4) {
            float4 cw = cp4[c4], ww = wr4[c4];
            a += cw.x * ww.x + cw.y * ww.y + cw.z * ww.z + cw.w * ww.w;
        }
        red[18 + tid] = a;
    }
    __syncthreads();
    if (t == 0) {
        float s = 0.f, q = 0.f;
        #pragma unroll
        for (int i = 0; i < 8; ++i) { s += red[i]; q += red[8 + i]; }
        const float inv = 1.0f / (float)(B_ * L_);
        float mean = s * inv;
        float var = q * inv - mean * mean;
        red[16] = mean; red[17] = rsqrtf(var + 1e-5f);
    }
    __syncthreads();

    // ---- phase 3: coalesced BN + FiLM + gelu + residual
    const float mean = red[16], rstd = red[17];
    const float rw = res_w[g];
    const int fb = t >> 5, tc = t & 31;
    const float gf = red[18 + 2 * fb];
    const float bb = red[18 + 2 * fb + 1];
    const u32 fswz = (u32)((fb & 7) << 4);
    const char* yrow = smem + fb * 4096;
    const size_t rowoff = ((size_t)fb * H_ + g) * L_;
    #pragma unroll
    for (int i = 0; i < 16; ++i) {
        int l = tc * 4 + 128 * i;
        uint2 yy = *(const uint2*)(yrow + (((u32)(2 * l)) ^ fswz));
        float4 xv = *(const float4*)&x[rowoff + l];
        float4 o;
        o.x = gelu_f((bf2f((u16)(yy.x & 0xFFFFu)) - mean) * rstd * gf + bb) + xv.x * rw;
        o.y = gelu_f((bf2f((u16)(yy.x >> 16))     - mean) * rstd * gf + bb) + xv.y * rw;
        o.z = gelu_f((bf2f((u16)(yy.y & 0xFFFFu)) - mean) * rstd * gf + bb) + xv.z * rw;
        o.w = gelu_f((bf2f((u16)(yy.y >> 16))     - mean) * rstd * gf + bb) + xv.w * rw;
        *(float4*)&out[rowoff + l] = o;
    }
}

// ---------------------------------------------------------------- launch
extern "C" void kernel_launch(void* const* d_in, const int* in_sizes, int n_in,
                              void* d_out, int out_size, void* d_ws, size_t ws_size,
                              hipStream_t stream) {
    const int expect[12] = {16777216, 2048, 262144, 512, 512, 65536,
                            32768, 32768, 512, 131072, 1024, 512};
    bool ok = (n_in == 12);
    if (ok) for (int i = 0; i < 12; ++i) if (in_sizes[i] != expect[i]) ok = false;
    if (!ok) {
        k_fill<<<(out_size + 255) / 256, 256, 0, stream>>>((float*)d_out, out_size, 1000.0f);
        return;
    }
    if (ws_size < (size_t)H_ * L_ * 4 + 4096) {
        k_fill<<<(out_size + 255) / 256, 256, 0, stream>>>((float*)d_out, out_size, 2000.0f);
        return;
    }

    const float* x          = (const float*)d_in[0];
    const float* cond       = (const float*)d_in[1];
    const float* linear_w   = (const float*)d_in[2];
    const float* linear_b   = (const float*)d_in[3];
    const float* log_dt     = (const float*)d_in[4];
    const float* C_ri       = (const float*)d_in[5];
    const float* log_A_real = (const float*)d_in[6];
    const float* A_imag     = (const float*)d_in[7];
    const float* Dp         = (const float*)d_in[8];
    const float* film_w     = (const float*)d_in[9];
    const float* film_b     = (const float*)d_in[10];
    const float* res_w      = (const float*)d_in[11];

    float* hy = (float*)d_out;   // f32-h fallback + final output

    char* w = (char*)d_ws;
    float* Kbuf = (float*)w;  w += (size_t)H_ * L_ * 4;          // 4 MB
    u16*   hb16 = (u16*)w;                                       // 33.5 MB (optional)
    const size_t need_bf16 = (size_t)H_ * L_ * 4 + (size_t)B_ * H_ * L_ * 2 + 4096;
    int bf16h = (ws_size >= need_bf16) ? 1 : 0;

    k_K4<<<H_, 256, 0, stream>>>(log_dt, C_ri, log_A_real, A_imag, Kbuf);
    dim3 gmm(L_ / 128, H_ / 128, B_);
    k_linear4<<<gmm, 512, 0, stream>>>(x, linear_w, linear_b, hy, hb16, bf16h);
    k_conv_mfma<<<H_, 512, 0, stream>>>(hy, hb16, hy, bf16h, Kbuf, Dp, x,
                                        cond, film_w, film_b, res_w);
}